// Round 7
// baseline (3373.454 us; speedup 1.0000x reference)
//
#include <hip/hip_runtime.h>
#include <stdint.h>

// FCOS bbox post-processing, B=4 images — f32 pipeline replicating the np/XLA
// reference op-by-op: sigmoid = 1/(1+exp(-x)) with PER-OP f32 rounding
// (exp correctly rounded via f64, then f32 add, f32 div), all box/IoU math in
// explicit __f*_rn (no FMA contraction), stable jax tie rules everywhere.

#define BN 4
#define NC 80
#define TOT 170720       // 128000+32000+8000+2000+720
#define KTOT 4720        // 1000*4+720
#define NWORDS 74        // ceil(4720/64)
#define TIE_CAP 4096
#define IMGSZ 320.0f

struct InPtrs {
  const float* cls[5];
  const float* bbox[5];
  const float* ctr[5];
};

__device__ __forceinline__ uint32_t f2s(float f) {
  uint32_t x = __float_as_uint(f);
  return (x & 0x80000000u) ? ~x : (x | 0x80000000u);
}
__device__ __forceinline__ float s2f(uint32_t s) {
  uint32_t x = (s & 0x80000000u) ? (s & 0x7fffffffu) : ~s;
  return __uint_as_float(x);
}
// np/XLA logistic: 1/(1+exp(-x)) with per-op f32 rounding.
// exp step: correctly-rounded f32 exp (via f64); then f32 add; f32 div.
__device__ __forceinline__ float sigmoid32(float v) {
  float e = (float)exp(-(double)v);          // CR f32 exp(-v)
  return __fdiv_rn(1.0f, __fadd_rn(1.0f, e));
}
__device__ __forceinline__ void lvl_of(int e, int& l, int& le) {
  if (e < 128000)      { l = 0; le = e; }
  else if (e < 160000) { l = 1; le = e - 128000; }
  else if (e < 168000) { l = 2; le = e - 160000; }
  else if (e < 170000) { l = 3; le = e - 168000; }
  else                 { l = 4; le = e - 170000; }
}
__device__ __forceinline__ int kl_of(int l) {
  constexpr int KL[5] = {1000, 1000, 1000, 1000, 720};
  return KL[l];
}
__device__ __forceinline__ float clip32(float v) {
  return fminf(fmaxf(v, 0.0f), IMGSZ);
}

// ---------------- init state ----------------
__global__ void k_init(uint32_t* __restrict__ mk, uint32_t* __restrict__ mpfx,
                       uint32_t* __restrict__ selcnt, uint32_t* __restrict__ tiecnt,
                       uint32_t* __restrict__ maxcb) {
  int t = threadIdx.x;
  if (t < 20) {
    mk[t] = (uint32_t)kl_of(t % 5);
    mpfx[t] = 0u;
    selcnt[t] = 0u;
    tiecnt[t] = 0u;
  }
  if (t < BN) maxcb[t] = 0u;
}

// ---------------- scores -> sortable u32 keys ----------------
__global__ void k_score(InPtrs in, uint32_t* __restrict__ su) {
  int b = blockIdx.y;
  int e = blockIdx.x * blockDim.x + threadIdx.x;
  if (e >= TOT) return;
  int l, le; lvl_of(e, l, le);
  constexpr int HWc[5] = {1600, 400, 100, 25, 9};
  int hw = HWc[l];
  int c = le % NC, p = le / NC;
  float v = in.cls[l][((size_t)b * NC + c) * hw + p];
  float s = sigmoid32(v);
  float m = (s > 0.025f) ? s : -1.0f;   // filter mask -> -1 (f32 weak-typed thr)
  su[(size_t)b * TOT + e] = f2s(m);
}

// ---------------- radix pass (16-bit digits, 2 passes) ----------------
__global__ void k_histp(const uint32_t* __restrict__ su, const uint32_t* __restrict__ mpfx,
                        uint32_t* __restrict__ hist, int pass) {
  int b = blockIdx.y;
  int e = blockIdx.x * blockDim.x + threadIdx.x;
  if (e >= TOT) return;
  int l, le; lvl_of(e, l, le);
  int bl = b * 5 + l;
  uint32_t key = su[(size_t)b * TOT + e];
  bool match = (pass == 0) ? true : ((key >> 16) == (mpfx[bl] >> 16));
  if (match) {
    uint32_t digit = (pass == 0) ? (key >> 16) : (key & 0xFFFFu);
    atomicAdd(&hist[(size_t)bl * 65536u + digit], 1u);
  }
}

__global__ void k_findp(const uint32_t* __restrict__ hist, uint32_t* __restrict__ mpfx,
                        uint32_t* __restrict__ mk, int pass) {
  int bl = blockIdx.x;
  uint32_t k = mk[bl];
  uint32_t pfx = mpfx[bl];
  const uint32_t* h = hist + (size_t)bl * 65536;
  __shared__ uint32_t sh[1024];
  int tid = threadIdx.x;
  int base = tid * 64;
  uint32_t s = 0;
  for (int i = 0; i < 64; i++) s += h[base + i];
  sh[tid] = s;
  __syncthreads();
  uint32_t above = 0;
  for (int t = tid + 1; t < 1024; t++) above += sh[t];
  if (above < k && above + s >= k) {
    uint32_t cum = above;
    for (int bin = base + 63; bin >= base; bin--) {
      uint32_t c = h[bin];
      if (cum < k && cum + c >= k) {
        if (pass == 0) mpfx[bl] = (uint32_t)bin << 16;
        else           mpfx[bl] = pfx | (uint32_t)bin;
        mk[bl] = k - cum;   // remaining needed within extended prefix
        break;
      }
      cum += c;
    }
  }
}

// ---------------- compact selected ----------------
__global__ void k_compact(const uint32_t* __restrict__ su, const uint32_t* __restrict__ mpfx,
                          uint32_t* __restrict__ selcnt, uint32_t* __restrict__ tiecnt,
                          uint32_t* __restrict__ selu, uint32_t* __restrict__ seli,
                          uint32_t* __restrict__ tiei) {
  int b = blockIdx.y;
  int e = blockIdx.x * blockDim.x + threadIdx.x;
  if (e >= TOT) return;
  int l, le; lvl_of(e, l, le);
  int bl = b * 5 + l;
  uint32_t u = su[(size_t)b * TOT + e];
  uint32_t C = mpfx[bl];   // complete cutoff key after 2 passes
  if (u > C) {
    uint32_t pos = atomicAdd(&selcnt[bl], 1u);
    selu[(size_t)bl * 1024 + pos] = u;
    seli[(size_t)bl * 1024 + pos] = (uint32_t)le;
  } else if (u == C) {
    uint32_t pos = atomicAdd(&tiecnt[bl], 1u);
    if (pos < TIE_CAP) tiei[(size_t)bl * TIE_CAP + pos] = (uint32_t)le;
  }
}

// Boundary ties: jax.lax.top_k is stable -> smallest indices first.
__global__ void k_ties(const uint32_t* __restrict__ mpfx, const uint32_t* __restrict__ mk,
                       const uint32_t* __restrict__ tiecnt, const uint32_t* __restrict__ tiei,
                       uint32_t* __restrict__ selu, uint32_t* __restrict__ seli) {
  int bl = blockIdx.x;
  int l = bl % 5;
  uint32_t C = mpfx[bl];
  uint32_t T = mk[bl];                       // ties needed (>=1)
  uint32_t G = (uint32_t)kl_of(l) - T;       // count(u > C)
  uint32_t Tc = tiecnt[bl];
  if (Tc > TIE_CAP) Tc = TIE_CAP;
  __shared__ uint32_t sh[TIE_CAP];
  for (uint32_t t = threadIdx.x; t < Tc; t += blockDim.x) sh[t] = tiei[(size_t)bl * TIE_CAP + t];
  __syncthreads();
  for (uint32_t t = threadIdx.x; t < Tc; t += blockDim.x) {
    uint32_t my = sh[t];
    uint32_t rank = 0;
    for (uint32_t q = 0; q < Tc; q++) rank += (sh[q] < my) ? 1u : 0u;   // asc index
    if (rank < T) {
      selu[(size_t)bl * 1024 + G + rank] = C;
      seli[(size_t)bl * 1024 + G + rank] = my;
    }
  }
}

// ---------------- exact rank within level (stable: smaller index first) ----------
__global__ void k_emit(InPtrs in, const uint32_t* __restrict__ selu, const uint32_t* __restrict__ seli,
                       float* __restrict__ ccs, uint32_t* __restrict__ ccl,
                       uint32_t* __restrict__ ccv, float* __restrict__ ccb) {
  int bl = blockIdx.x;
  int b = bl / 5, l = bl % 5;
  int k = kl_of(l);
  __shared__ uint32_t su_s[1024];
  __shared__ uint32_t si_s[1024];
  int tid = threadIdx.x;
  if (tid < k) { su_s[tid] = selu[(size_t)bl * 1024 + tid]; si_s[tid] = seli[(size_t)bl * 1024 + tid]; }
  __syncthreads();
  if (tid >= k) return;
  uint32_t u = su_s[tid];
  uint32_t idx = si_s[tid];
  int rank = 0;
  for (int j = 0; j < k; j++) {
    uint32_t uj = su_s[j];
    uint32_t ij = si_s[j];
    rank += ((uj > u) || (uj == u && ij < idx)) ? 1 : 0;   // stable top_k
  }
  constexpr int Wc[5]  = {40, 20, 10, 5, 3};
  constexpr int HWc[5] = {1600, 400, 100, 25, 9};
  constexpr float Sc[5] = {8.f, 16.f, 32.f, 64.f, 128.f};
  constexpr int COFF[5] = {0, 1000, 2000, 3000, 4000};
  int w = Wc[l], hw = HWc[l];
  float ms = s2f(u);
  int valid = (ms > 0.025f) ? 1 : 0;
  int p = (int)idx / NC, c = (int)idx % NC;
  int x = p % w, y = p / w;
  float sf = sigmoid32(in.ctr[l][(size_t)b * hw + p]);
  float score = valid ? __fmul_rn(ms, sf) : -1.0f;
  float px = __fmul_rn(__fadd_rn((float)x, 0.5f), Sc[l]);   // exact
  float py = __fmul_rn(__fadd_rn((float)y, 0.5f), Sc[l]);
  size_t bb = (size_t)b * 4 * hw;
  float d0 = in.bbox[l][bb + 0 * hw + p];
  float d1 = in.bbox[l][bb + 1 * hw + p];
  float d2 = in.bbox[l][bb + 2 * hw + p];
  float d3 = in.bbox[l][bb + 3 * hw + p];
  float x1 = clip32(__fsub_rn(px, d0)), y1 = clip32(__fsub_rn(py, d1));
  float x2 = clip32(__fadd_rn(px, d2)), y2 = clip32(__fadd_rn(py, d3));
  int o = b * KTOT + COFF[l] + rank;
  ccs[o] = score;
  ccl[o] = (uint32_t)c;
  ccv[o] = (uint32_t)valid;
  ccb[(size_t)o * 4 + 0] = x1; ccb[(size_t)o * 4 + 1] = y1;
  ccb[(size_t)o * 4 + 2] = x2; ccb[(size_t)o * 4 + 3] = y2;
}

// ---------------- per-image stable descending sort (rank method) ----------------
__global__ void k_sortimg(const float* __restrict__ ccs, const uint32_t* __restrict__ ccl,
                          const uint32_t* __restrict__ ccv, const float* __restrict__ ccb,
                          float* __restrict__ ss, uint32_t* __restrict__ sl,
                          uint32_t* __restrict__ sv, float* __restrict__ sb,
                          uint32_t* __restrict__ maxcb) {
  int b = blockIdx.y;
  __shared__ uint32_t key[KTOT];   // 18.9 KB
  for (int e = threadIdx.x; e < KTOT; e += blockDim.x) key[e] = f2s(ccs[(size_t)b * KTOT + e]);
  __syncthreads();
  int e = blockIdx.x * 1024 + threadIdx.x;
  if (e >= KTOT) return;
  uint32_t ke = key[e];
  int rank = 0;
  for (int j = 0; j < KTOT; j++) {
    uint32_t kj = key[j];
    rank += ((kj > ke) || (kj == ke && j < e)) ? 1 : 0;  // stable: earlier pos first
  }
  int sidx = b * KTOT + e;
  int d = b * KTOT + rank;
  ss[d] = ccs[sidx];
  sl[d] = ccl[sidx];
  sv[d] = ccv[sidx];
  float b0 = ccb[(size_t)sidx * 4 + 0], b1 = ccb[(size_t)sidx * 4 + 1];
  float b2 = ccb[(size_t)sidx * 4 + 2], b3 = ccb[(size_t)sidx * 4 + 3];
  sb[(size_t)d * 4 + 0] = b0; sb[(size_t)d * 4 + 1] = b1;
  sb[(size_t)d * 4 + 2] = b2; sb[(size_t)d * 4 + 3] = b3;
  float mx = fmaxf(fmaxf(b0, b1), fmaxf(b2, b3));   // coords >= 0 -> uint-bit max ok
  atomicMax(&maxcb[b], __float_as_uint(mx));
}

// ---------------- per-class offset boxes + areas (f32) ----------------
__global__ void k_offset(const float* __restrict__ sb, const uint32_t* __restrict__ sl,
                         const uint32_t* __restrict__ maxcb,
                         float* __restrict__ ob, float* __restrict__ oa) {
  int r = blockIdx.x * blockDim.x + threadIdx.x;
  if (r >= BN * KTOT) return;
  int b = r / KTOT;
  float scale = __fadd_rn(__uint_as_float(maxcb[b]), 1.0f);
  float offv = __fmul_rn((float)sl[r], scale);
  float x1 = __fadd_rn(sb[(size_t)r * 4 + 0], offv);
  float y1 = __fadd_rn(sb[(size_t)r * 4 + 1], offv);
  float x2 = __fadd_rn(sb[(size_t)r * 4 + 2], offv);
  float y2 = __fadd_rn(sb[(size_t)r * 4 + 3], offv);
  ob[(size_t)r * 4 + 0] = x1; ob[(size_t)r * 4 + 1] = y1;
  ob[(size_t)r * 4 + 2] = x2; ob[(size_t)r * 4 + 3] = y2;
  oa[r] = __fmul_rn(__fsub_rn(x2, x1), __fsub_rn(y2, y1));
}

// ---------------- IoU bitmask matrix (f32, np op chain) ----------------
__global__ void k_mask(const float* __restrict__ ob, const float* __restrict__ oa,
                       unsigned long long* __restrict__ mask) {
  int b = blockIdx.y;
  int i = blockIdx.x * 256 + threadIdx.x;
  bool act = (i < KTOT);
  __shared__ float tx1[1024], ty1[1024], tx2[1024], ty2[1024], ta[1024];  // 20 KB
  float bx1 = 0, by1 = 0, bx2 = 0, by2 = 0, bai = 0;
  if (act) {
    size_t g = ((size_t)b * KTOT + i) * 4;
    bx1 = ob[g]; by1 = ob[g + 1]; bx2 = ob[g + 2]; by2 = ob[g + 3];
    bai = oa[(size_t)b * KTOT + i];
  }
  unsigned long long* mrow = mask + ((size_t)b * KTOT + (size_t)(act ? i : 0)) * NWORDS;
  for (int t = 0; t < 5; t++) {
    int jbase = t * 1024;
    int cnt = min(1024, KTOT - jbase);
    __syncthreads();
    for (int j = threadIdx.x; j < cnt; j += 256) {
      size_t g = ((size_t)b * KTOT + jbase + j) * 4;
      tx1[j] = ob[g]; ty1[j] = ob[g + 1]; tx2[j] = ob[g + 2]; ty2[j] = ob[g + 3];
      ta[j] = oa[(size_t)b * KTOT + jbase + j];
    }
    __syncthreads();
    if (act) {
      int nw = (cnt + 63) >> 6;
      for (int w = 0; w < nw; w++) {
        unsigned long long bits = 0ull;
        int j0 = w * 64;
        int jn = min(64, cnt - j0);
        for (int jj = 0; jj < jn; jj++) {
          int j = jbase + j0 + jj;
          if (j > i) {
            int jl = j0 + jj;
            float ltx = fmaxf(bx1, tx1[jl]), lty = fmaxf(by1, ty1[jl]);
            float rbx = fminf(bx2, tx2[jl]), rby = fminf(by2, ty2[jl]);
            float wd = fmaxf(__fsub_rn(rbx, ltx), 0.0f);
            float hg = fmaxf(__fsub_rn(rby, lty), 0.0f);
            float inter = __fmul_rn(wd, hg);
            float asum = __fadd_rn(bai, ta[jl]);
            float uni  = __fsub_rn(asum, inter);
            float iou  = (uni > 0.0f) ? __fdiv_rn(inter, uni) : 0.0f;
            if (iou > 0.5f) bits |= (1ull << jj);
          }
        }
        mrow[t * 16 + w] = bits;
      }
    }
  }
}

// ---------------- serial greedy NMS, one wave per image ----------------
__global__ void k_nms(const unsigned long long* __restrict__ mask, const uint32_t* __restrict__ sv,
                      uint32_t* __restrict__ keep) {
  int b = blockIdx.x;
  int lane = threadIdx.x;
  const unsigned long long* mb = mask + (size_t)b * KTOT * NWORDS;
  const uint32_t* svb = sv + (size_t)b * KTOT;
  uint32_t* kb = keep + (size_t)b * KTOT;
  unsigned long long r0 = 0ull, r1 = 0ull;
  unsigned long long p0[4], p1[4];
#pragma unroll
  for (int u = 0; u < 4; u++) {
    p0[u] = mb[(size_t)u * NWORDS + lane];
    p1[u] = (lane + 64 < NWORDS) ? mb[(size_t)u * NWORDS + lane + 64] : 0ull;
  }
  for (int i = 0; i < KTOT; i += 4) {
#pragma unroll
    for (int u = 0; u < 4; u++) {
      int ii = i + u;
      int w = ii >> 6, bit = ii & 63;
      unsigned long long rw = (w < 64) ? __shfl(r0, w, 64) : __shfl(r1, w - 64, 64);
      bool kp = (svb[ii] != 0u) && !((rw >> bit) & 1ull);
      if (kp) { r0 |= p0[u]; r1 |= p1[u]; }
      if (lane == 0) kb[ii] = kp ? 1u : 0u;
      int ni = ii + 4;   // prefetch distance 4
      if (ni < KTOT) {
        p0[u] = mb[(size_t)ni * NWORDS + lane];
        p1[u] = (lane + 64 < NWORDS) ? mb[(size_t)ni * NWORDS + lane + 64] : 0ull;
      } else {
        p0[u] = 0ull; p1[u] = 0ull;
      }
    }
  }
}

// ---------------- final outputs ----------------
__global__ void k_out(const float* __restrict__ ss, const uint32_t* __restrict__ sl,
                      const float* __restrict__ sb, const uint32_t* __restrict__ keep,
                      float* __restrict__ out) {
  int r = blockIdx.x * blockDim.x + threadIdx.x;
  if (r >= BN * KTOT) return;
  out[(size_t)r * 5 + 0] = sb[(size_t)r * 4 + 0];
  out[(size_t)r * 5 + 1] = sb[(size_t)r * 4 + 1];
  out[(size_t)r * 5 + 2] = sb[(size_t)r * 4 + 2];
  out[(size_t)r * 5 + 3] = sb[(size_t)r * 4 + 3];
  out[(size_t)r * 5 + 4] = ss[r];
  out[(size_t)BN * KTOT * 5 + r] = (float)sl[r];
  out[(size_t)BN * KTOT * 6 + r] = keep[r] ? 1.0f : 0.0f;
}

extern "C" void kernel_launch(void* const* d_in, const int* in_sizes, int n_in,
                              void* d_out, int out_size, void* d_ws, size_t ws_size,
                              hipStream_t stream) {
  InPtrs ip;
  for (int l = 0; l < 5; l++) {
    ip.cls[l]  = (const float*)d_in[3 * l + 0];
    ip.bbox[l] = (const float*)d_in[3 * l + 1];
    ip.ctr[l]  = (const float*)d_in[3 * l + 2];
  }

  size_t off = 0;
  auto alloc = [&](size_t n) {
    char* p = (char*)d_ws + off;
    off = (off + n + 255) & ~(size_t)255;
    return p;
  };
  const size_t SU_BYTES   = (size_t)BN * TOT * 4;           // 2.73 MB
  const size_t HIST_BYTES = 20ull * 65536 * 4;              // 5.24 MB
  const size_t MASK_BYTES = (size_t)BN * KTOT * NWORDS * 8; // 11.18 MB
  size_t region0 = ((SU_BYTES + 255) & ~(size_t)255) + HIST_BYTES;
  if (MASK_BYTES > region0) region0 = MASK_BYTES;
  char* r0p = (char*)alloc(region0);
  uint32_t* su   = (uint32_t*)r0p;
  uint32_t* hist = (uint32_t*)(r0p + ((SU_BYTES + 255) & ~(size_t)255));
  unsigned long long* mask = (unsigned long long*)r0p;

  uint32_t* mpfx   = (uint32_t*)alloc(20 * 4);
  uint32_t* mk     = (uint32_t*)alloc(20 * 4);
  uint32_t* selcnt = (uint32_t*)alloc(20 * 4);
  uint32_t* tiecnt = (uint32_t*)alloc(20 * 4);
  uint32_t* maxcb  = (uint32_t*)alloc(BN * 4);
  uint32_t* selu   = (uint32_t*)alloc(20ull * 1024 * 4);
  uint32_t* seli   = (uint32_t*)alloc(20ull * 1024 * 4);
  uint32_t* tiei   = (uint32_t*)alloc(20ull * TIE_CAP * 4);
  float*    ccs    = (float*)   alloc((size_t)BN * KTOT * 4);
  uint32_t* ccl    = (uint32_t*)alloc((size_t)BN * KTOT * 4);
  uint32_t* ccv    = (uint32_t*)alloc((size_t)BN * KTOT * 4);
  float*    ccb    = (float*)   alloc((size_t)BN * KTOT * 16);
  float*    ss     = (float*)   alloc((size_t)BN * KTOT * 4);
  uint32_t* sl     = (uint32_t*)alloc((size_t)BN * KTOT * 4);
  uint32_t* sv     = (uint32_t*)alloc((size_t)BN * KTOT * 4);
  float*    sb     = (float*)   alloc((size_t)BN * KTOT * 16);
  float*    ob     = (float*)   alloc((size_t)BN * KTOT * 16);
  float*    oa     = (float*)   alloc((size_t)BN * KTOT * 4);
  uint32_t* keepb  = (uint32_t*)alloc((size_t)BN * KTOT * 4);
  (void)ws_size; (void)in_sizes; (void)n_in; (void)out_size;

  k_init<<<1, 64, 0, stream>>>(mk, mpfx, selcnt, tiecnt, maxcb);

  dim3 gscan((TOT + 255) / 256, BN);
  k_score<<<gscan, 256, 0, stream>>>(ip, su);
  for (int pass = 0; pass < 2; pass++) {
    hipMemsetAsync(hist, 0, HIST_BYTES, stream);
    k_histp<<<gscan, 256, 0, stream>>>(su, mpfx, hist, pass);
    k_findp<<<20, 1024, 0, stream>>>(hist, mpfx, mk, pass);
  }
  k_compact<<<gscan, 256, 0, stream>>>(su, mpfx, selcnt, tiecnt, selu, seli, tiei);
  k_ties<<<20, 256, 0, stream>>>(mpfx, mk, tiecnt, tiei, selu, seli);
  k_emit<<<20, 1024, 0, stream>>>(ip, selu, seli, ccs, ccl, ccv, ccb);
  k_sortimg<<<dim3(5, BN), 1024, 0, stream>>>(ccs, ccl, ccv, ccb, ss, sl, sv, sb, maxcb);
  k_offset<<<(BN * KTOT + 255) / 256, 256, 0, stream>>>(sb, sl, maxcb, ob, oa);
  k_mask<<<dim3(19, BN), 256, 0, stream>>>(ob, oa, mask);
  k_nms<<<BN, 64, 0, stream>>>(mask, sv, keepb);
  k_out<<<(BN * KTOT + 255) / 256, 256, 0, stream>>>(ss, sl, sb, keepb, (float*)d_out);
}

// Round 8
// 2176.431 us; speedup vs baseline: 1.5500x; 1.5500x over previous
//
#include <hip/hip_runtime.h>
#include <stdint.h>

// FCOS bbox post-processing, B=4 images — bit-exact np/XLA-f32 replication
// (R7 passing semantics), optimized:
//  - k_nms: blocked greedy NMS (readlane diagonal scan + transposed diag
//    blocks + batched row fetch) instead of per-item serialization.
//  - k_histp: wave-aggregated atomic for the hot -1.0 bin.
//  - k_mask: float4 LDS tiles, area recomputed with identical rounding chain;
//    also emits transposed 64x64 diagonal blocks for k_nms.
//  - k_sortimg: b128 LDS key reads.

#define BN 4
#define NC 80
#define TOT 170720       // 128000+32000+8000+2000+720
#define KTOT 4720        // 1000*4+720
#define NWORDS 74        // ceil(4720/64)
#define NWIN 74
#define TIE_CAP 4096
#define IMGSZ 320.0f
#define PB 16            // phase-2 row-fetch batch

struct InPtrs {
  const float* cls[5];
  const float* bbox[5];
  const float* ctr[5];
};

__device__ __forceinline__ uint32_t f2s(float f) {
  uint32_t x = __float_as_uint(f);
  return (x & 0x80000000u) ? ~x : (x | 0x80000000u);
}
__device__ __forceinline__ float s2f(uint32_t s) {
  uint32_t x = (s & 0x80000000u) ? (s & 0x7fffffffu) : ~s;
  return __uint_as_float(x);
}
// np/XLA logistic: 1/(1+exp(-x)) with per-op f32 rounding.
__device__ __forceinline__ float sigmoid32(float v) {
  float e = (float)exp(-(double)v);          // CR f32 exp(-v)
  return __fdiv_rn(1.0f, __fadd_rn(1.0f, e));
}
__device__ __forceinline__ void lvl_of(int e, int& l, int& le) {
  if (e < 128000)      { l = 0; le = e; }
  else if (e < 160000) { l = 1; le = e - 128000; }
  else if (e < 168000) { l = 2; le = e - 160000; }
  else if (e < 170000) { l = 3; le = e - 168000; }
  else                 { l = 4; le = e - 170000; }
}
__device__ __forceinline__ int kl_of(int l) {
  constexpr int KL[5] = {1000, 1000, 1000, 1000, 720};
  return KL[l];
}
__device__ __forceinline__ float clip32(float v) {
  return fminf(fmaxf(v, 0.0f), IMGSZ);
}

// ---------------- init state ----------------
__global__ void k_init(uint32_t* __restrict__ mk, uint32_t* __restrict__ mpfx,
                       uint32_t* __restrict__ selcnt, uint32_t* __restrict__ tiecnt,
                       uint32_t* __restrict__ maxcb) {
  int t = threadIdx.x;
  if (t < 20) {
    mk[t] = (uint32_t)kl_of(t % 5);
    mpfx[t] = 0u;
    selcnt[t] = 0u;
    tiecnt[t] = 0u;
  }
  if (t < BN) maxcb[t] = 0u;
}

// ---------------- scores -> sortable u32 keys ----------------
__global__ void k_score(InPtrs in, uint32_t* __restrict__ su) {
  int b = blockIdx.y;
  int e = blockIdx.x * blockDim.x + threadIdx.x;
  if (e >= TOT) return;
  int l, le; lvl_of(e, l, le);
  constexpr int HWc[5] = {1600, 400, 100, 25, 9};
  int hw = HWc[l];
  int c = le % NC, p = le / NC;
  float v = in.cls[l][((size_t)b * NC + c) * hw + p];
  float s = sigmoid32(v);
  float m = (s > 0.025f) ? s : -1.0f;
  su[(size_t)b * TOT + e] = f2s(m);
}

// ---------------- radix pass (16-bit digits, 2 passes) ----------------
// Hot-bin fix: keys equal to f2s(-1.0f)=0x407FFFFF (masked scores, ~14% of
// all keys) are wave-aggregated into one atomic. Guard excludes the single
// wave straddling the level-3/4 boundary (base 169984, not bl-uniform).
__global__ void k_histp(const uint32_t* __restrict__ su, const uint32_t* __restrict__ mpfx,
                        uint32_t* __restrict__ hist, int pass) {
  int b = blockIdx.y;
  int e = blockIdx.x * blockDim.x + threadIdx.x;
  if (e >= TOT) return;
  int l, le; lvl_of(e, l, le);
  int bl = b * 5 + l;
  uint32_t key = su[(size_t)b * TOT + e];
  bool match = (pass == 0) ? true : ((key >> 16) == (mpfx[bl] >> 16));
  if (match) {
    uint32_t digit = (pass == 0) ? (key >> 16) : (key & 0xFFFFu);
    bool neg = (key == 0x407FFFFFu) && ((e & ~63) != 169984);
    if (neg) {
      unsigned long long mb2 = __ballot(1);
      int lead = __ffsll((long long)mb2) - 1;
      if ((threadIdx.x & 63) == lead)
        atomicAdd(&hist[(size_t)bl * 65536u + digit], (uint32_t)__popcll(mb2));
    } else {
      atomicAdd(&hist[(size_t)bl * 65536u + digit], 1u);
    }
  }
}

__global__ void k_findp(const uint32_t* __restrict__ hist, uint32_t* __restrict__ mpfx,
                        uint32_t* __restrict__ mk, int pass) {
  int bl = blockIdx.x;
  uint32_t k = mk[bl];
  uint32_t pfx = mpfx[bl];
  const uint32_t* h = hist + (size_t)bl * 65536;
  __shared__ uint32_t sh[1024];
  int tid = threadIdx.x;
  int base = tid * 64;
  uint32_t s = 0;
  for (int i = 0; i < 64; i++) s += h[base + i];
  sh[tid] = s;
  __syncthreads();
  uint32_t above = 0;
  for (int t = tid + 1; t < 1024; t++) above += sh[t];
  if (above < k && above + s >= k) {
    uint32_t cum = above;
    for (int bin = base + 63; bin >= base; bin--) {
      uint32_t c = h[bin];
      if (cum < k && cum + c >= k) {
        if (pass == 0) mpfx[bl] = (uint32_t)bin << 16;
        else           mpfx[bl] = pfx | (uint32_t)bin;
        mk[bl] = k - cum;
        break;
      }
      cum += c;
    }
  }
}

// ---------------- compact selected ----------------
__global__ void k_compact(const uint32_t* __restrict__ su, const uint32_t* __restrict__ mpfx,
                          uint32_t* __restrict__ selcnt, uint32_t* __restrict__ tiecnt,
                          uint32_t* __restrict__ selu, uint32_t* __restrict__ seli,
                          uint32_t* __restrict__ tiei) {
  int b = blockIdx.y;
  int e = blockIdx.x * blockDim.x + threadIdx.x;
  if (e >= TOT) return;
  int l, le; lvl_of(e, l, le);
  int bl = b * 5 + l;
  uint32_t u = su[(size_t)b * TOT + e];
  uint32_t C = mpfx[bl];
  if (u > C) {
    uint32_t pos = atomicAdd(&selcnt[bl], 1u);
    selu[(size_t)bl * 1024 + pos] = u;
    seli[(size_t)bl * 1024 + pos] = (uint32_t)le;
  } else if (u == C) {
    uint32_t pos = atomicAdd(&tiecnt[bl], 1u);
    if (pos < TIE_CAP) tiei[(size_t)bl * TIE_CAP + pos] = (uint32_t)le;
  }
}

// Boundary ties: stable top_k -> smallest indices first.
__global__ void k_ties(const uint32_t* __restrict__ mpfx, const uint32_t* __restrict__ mk,
                       const uint32_t* __restrict__ tiecnt, const uint32_t* __restrict__ tiei,
                       uint32_t* __restrict__ selu, uint32_t* __restrict__ seli) {
  int bl = blockIdx.x;
  int l = bl % 5;
  uint32_t C = mpfx[bl];
  uint32_t T = mk[bl];
  uint32_t G = (uint32_t)kl_of(l) - T;
  uint32_t Tc = tiecnt[bl];
  if (Tc > TIE_CAP) Tc = TIE_CAP;
  __shared__ uint32_t sh[TIE_CAP];
  for (uint32_t t = threadIdx.x; t < Tc; t += blockDim.x) sh[t] = tiei[(size_t)bl * TIE_CAP + t];
  __syncthreads();
  for (uint32_t t = threadIdx.x; t < Tc; t += blockDim.x) {
    uint32_t my = sh[t];
    uint32_t rank = 0;
    for (uint32_t q = 0; q < Tc; q++) rank += (sh[q] < my) ? 1u : 0u;
    if (rank < T) {
      selu[(size_t)bl * 1024 + G + rank] = C;
      seli[(size_t)bl * 1024 + G + rank] = my;
    }
  }
}

// ---------------- exact rank within level + emit (f32, __f*_rn chain) ----------
__global__ void k_emit(InPtrs in, const uint32_t* __restrict__ selu, const uint32_t* __restrict__ seli,
                       float* __restrict__ ccs, uint32_t* __restrict__ ccl,
                       uint32_t* __restrict__ ccv, float* __restrict__ ccb) {
  int bl = blockIdx.x;
  int b = bl / 5, l = bl % 5;
  int k = kl_of(l);
  __shared__ uint32_t su_s[1024];
  __shared__ uint32_t si_s[1024];
  int tid = threadIdx.x;
  if (tid < k) { su_s[tid] = selu[(size_t)bl * 1024 + tid]; si_s[tid] = seli[(size_t)bl * 1024 + tid]; }
  __syncthreads();
  if (tid >= k) return;
  uint32_t u = su_s[tid];
  uint32_t idx = si_s[tid];
  int rank = 0;
  for (int j = 0; j < k; j++) {
    uint32_t uj = su_s[j];
    uint32_t ij = si_s[j];
    rank += ((uj > u) || (uj == u && ij < idx)) ? 1 : 0;
  }
  constexpr int Wc[5]  = {40, 20, 10, 5, 3};
  constexpr int HWc[5] = {1600, 400, 100, 25, 9};
  constexpr float Sc[5] = {8.f, 16.f, 32.f, 64.f, 128.f};
  constexpr int COFF[5] = {0, 1000, 2000, 3000, 4000};
  int w = Wc[l], hw = HWc[l];
  float ms = s2f(u);
  int valid = (ms > 0.025f) ? 1 : 0;
  int p = (int)idx / NC, c = (int)idx % NC;
  int x = p % w, y = p / w;
  float sf = sigmoid32(in.ctr[l][(size_t)b * hw + p]);
  float score = valid ? __fmul_rn(ms, sf) : -1.0f;
  float px = __fmul_rn(__fadd_rn((float)x, 0.5f), Sc[l]);
  float py = __fmul_rn(__fadd_rn((float)y, 0.5f), Sc[l]);
  size_t bb = (size_t)b * 4 * hw;
  float d0 = in.bbox[l][bb + 0 * hw + p];
  float d1 = in.bbox[l][bb + 1 * hw + p];
  float d2 = in.bbox[l][bb + 2 * hw + p];
  float d3 = in.bbox[l][bb + 3 * hw + p];
  float x1 = clip32(__fsub_rn(px, d0)), y1 = clip32(__fsub_rn(py, d1));
  float x2 = clip32(__fadd_rn(px, d2)), y2 = clip32(__fadd_rn(py, d3));
  int o = b * KTOT + COFF[l] + rank;
  ccs[o] = score;
  ccl[o] = (uint32_t)c;
  ccv[o] = (uint32_t)valid;
  ccb[(size_t)o * 4 + 0] = x1; ccb[(size_t)o * 4 + 1] = y1;
  ccb[(size_t)o * 4 + 2] = x2; ccb[(size_t)o * 4 + 3] = y2;
}

// ---------------- per-image stable descending sort (rank method) ----------------
__global__ void k_sortimg(const float* __restrict__ ccs, const uint32_t* __restrict__ ccl,
                          const uint32_t* __restrict__ ccv, const float* __restrict__ ccb,
                          float* __restrict__ ss, uint32_t* __restrict__ sl,
                          uint32_t* __restrict__ sv, float* __restrict__ sb,
                          uint32_t* __restrict__ maxcb) {
  int b = blockIdx.y;
  __shared__ uint32_t key[KTOT];   // 18.9 KB, 16B-aligned
  for (int e = threadIdx.x; e < KTOT; e += blockDim.x) key[e] = f2s(ccs[(size_t)b * KTOT + e]);
  __syncthreads();
  int e = blockIdx.x * 1024 + threadIdx.x;
  if (e >= KTOT) return;
  uint32_t ke = key[e];
  int rank = 0;
  const uint4* k4 = (const uint4*)key;
  for (int j4 = 0; j4 < KTOT / 4; j4++) {   // b128 LDS reads: 4 keys/read
    uint4 kk = k4[j4];
    int j = j4 * 4;
    rank += ((kk.x > ke) || (kk.x == ke && (j + 0) < e)) ? 1 : 0;
    rank += ((kk.y > ke) || (kk.y == ke && (j + 1) < e)) ? 1 : 0;
    rank += ((kk.z > ke) || (kk.z == ke && (j + 2) < e)) ? 1 : 0;
    rank += ((kk.w > ke) || (kk.w == ke && (j + 3) < e)) ? 1 : 0;
  }
  int sidx = b * KTOT + e;
  int d = b * KTOT + rank;
  ss[d] = ccs[sidx];
  sl[d] = ccl[sidx];
  sv[d] = ccv[sidx];
  float b0 = ccb[(size_t)sidx * 4 + 0], b1 = ccb[(size_t)sidx * 4 + 1];
  float b2 = ccb[(size_t)sidx * 4 + 2], b3 = ccb[(size_t)sidx * 4 + 3];
  sb[(size_t)d * 4 + 0] = b0; sb[(size_t)d * 4 + 1] = b1;
  sb[(size_t)d * 4 + 2] = b2; sb[(size_t)d * 4 + 3] = b3;
  float mx = fmaxf(fmaxf(b0, b1), fmaxf(b2, b3));
  atomicMax(&maxcb[b], __float_as_uint(mx));
}

// ---------------- valid bits -> bitmask words ----------------
__global__ void k_bits(const uint32_t* __restrict__ sv, unsigned long long* __restrict__ vbits) {
  int w = blockIdx.x, b = blockIdx.y, lane = threadIdx.x;
  int e = w * 64 + lane;
  int pred = (e < KTOT) ? (sv[(size_t)b * KTOT + e] != 0u) : 0;
  unsigned long long m = __ballot(pred);
  if (lane == 0) vbits[b * NWIN + w] = m;
}

// ---------------- per-class offset boxes (f32) ----------------
__global__ void k_offset(const float* __restrict__ sb, const uint32_t* __restrict__ sl,
                         const uint32_t* __restrict__ maxcb, float* __restrict__ ob) {
  int r = blockIdx.x * blockDim.x + threadIdx.x;
  if (r >= BN * KTOT) return;
  int b = r / KTOT;
  float scale = __fadd_rn(__uint_as_float(maxcb[b]), 1.0f);
  float offv = __fmul_rn((float)sl[r], scale);
  float x1 = __fadd_rn(sb[(size_t)r * 4 + 0], offv);
  float y1 = __fadd_rn(sb[(size_t)r * 4 + 1], offv);
  float x2 = __fadd_rn(sb[(size_t)r * 4 + 2], offv);
  float y2 = __fadd_rn(sb[(size_t)r * 4 + 3], offv);
  ob[(size_t)r * 4 + 0] = x1; ob[(size_t)r * 4 + 1] = y1;
  ob[(size_t)r * 4 + 2] = x2; ob[(size_t)r * 4 + 3] = y2;
}

// ---------------- IoU bitmask matrix + transposed diagonal blocks ----------------
// Area recomputed with the IDENTICAL __f*_rn chain as before -> bit-equal.
__global__ void k_mask(const float* __restrict__ ob, unsigned long long* __restrict__ mask,
                       unsigned long long* __restrict__ tdiag) {
  int b = blockIdx.y;
  int i = blockIdx.x * 256 + threadIdx.x;
  bool act = (i < KTOT);
  __shared__ float4 tb[1024];   // 16 KB
  float bx1 = 0, by1 = 0, bx2 = 0, by2 = 0, bai = 0;
  if (act) {
    float4 v = ((const float4*)ob)[(size_t)b * KTOT + i];
    bx1 = v.x; by1 = v.y; bx2 = v.z; by2 = v.w;
    bai = __fmul_rn(__fsub_rn(bx2, bx1), __fsub_rn(by2, by1));
  }
  unsigned long long dw = 0ull;
  int myw = i >> 6;
  unsigned long long* mrow = mask + ((size_t)b * KTOT + (size_t)(act ? i : 0)) * NWORDS;
  for (int t = 0; t < 5; t++) {
    int jbase = t * 1024;
    int cnt = min(1024, KTOT - jbase);
    __syncthreads();
    for (int j = threadIdx.x; j < cnt; j += 256)
      tb[j] = ((const float4*)ob)[(size_t)b * KTOT + jbase + j];
    __syncthreads();
    if (act) {
      int nw = (cnt + 63) >> 6;
      for (int w = 0; w < nw; w++) {
        unsigned long long bits = 0ull;
        int j0 = w * 64;
        int jn = min(64, cnt - j0);
        for (int jj = 0; jj < jn; jj++) {
          int j = jbase + j0 + jj;
          if (j > i) {
            float4 o = tb[j0 + jj];
            float ta_ = __fmul_rn(__fsub_rn(o.z, o.x), __fsub_rn(o.w, o.y));
            float ltx = fmaxf(bx1, o.x), lty = fmaxf(by1, o.y);
            float rbx = fminf(bx2, o.z), rby = fminf(by2, o.w);
            float wd = fmaxf(__fsub_rn(rbx, ltx), 0.0f);
            float hg = fmaxf(__fsub_rn(rby, lty), 0.0f);
            float inter = __fmul_rn(wd, hg);
            float asum = __fadd_rn(bai, ta_);
            float uni  = __fsub_rn(asum, inter);
            float iou  = (uni > 0.0f) ? __fdiv_rn(inter, uni) : 0.0f;
            if (iou > 0.5f) bits |= (1ull << jj);
          }
        }
        mrow[(size_t)t * 16 + w] = bits;
        if (t * 16 + w == myw) dw = bits;   // own-window diagonal word
      }
    }
  }
  // transpose 64x64 diagonal block in-wave (column j = ballot of row bits j)
  int lane = threadIdx.x & 63;
  unsigned long long col = 0ull;
#pragma unroll
  for (int j = 0; j < 64; j++) {
    unsigned long long bal = __ballot((int)((dw >> j) & 1ull));
    if (lane == j) col = bal;
  }
  if (myw < NWIN) tdiag[((size_t)b * NWIN + (size_t)myw) * 64 + lane] = col;
}

// ---------------- blocked greedy NMS, one wave per image ----------------
// Per 64-item window: (1) readlane serial scan resolves within-window keeps
// using the transposed diagonal block; (2) kept rows OR'd into the register-
// resident suppressed bitmask (words 2*lane, 2*lane+1) with 16-deep batched
// uint4 loads. Same greedy recurrence as the per-item version -> same bits.
__global__ void k_nms(const unsigned long long* __restrict__ mask,
                      const unsigned long long* __restrict__ tdiag,
                      const unsigned long long* __restrict__ vbits,
                      unsigned long long* __restrict__ keepw) {
  int b = blockIdx.x;
  int lane = threadIdx.x;
  const unsigned long long* mb = mask + (size_t)b * KTOT * NWORDS;
  unsigned long long rw0 = 0ull, rw1 = 0ull;   // suppressed words 2*lane, 2*lane+1
  unsigned long long T = tdiag[((size_t)b * NWIN + 0) * 64 + lane];
  unsigned long long sval = vbits[b * NWIN + 0];
  for (int w = 0; w < NWIN; w++) {
    unsigned long long Tn = 0ull, svaln = 0ull;
    if (w + 1 < NWIN) {
      Tn = tdiag[((size_t)b * NWIN + (w + 1)) * 64 + lane];
      svaln = vbits[b * NWIN + (w + 1)];
    }
    int lsrc = w >> 1;
    unsigned long long sa = __shfl(rw0, lsrc, 64);
    unsigned long long sb2 = __shfl(rw1, lsrc, 64);
    unsigned long long s_in = (w & 1) ? sb2 : sa;
    unsigned int supb = (unsigned int)((s_in >> lane) & 1ull);
    unsigned int Tlo = (unsigned int)T, Thi = (unsigned int)(T >> 32);
    unsigned int svlo = (unsigned int)sval, svhi = (unsigned int)(sval >> 32);
    unsigned long long kw = 0ull;
#pragma unroll
    for (int i = 0; i < 64; i++) {
      unsigned int si = (unsigned int)__builtin_amdgcn_readlane((int)supb, i);
      unsigned int vi = ((i < 32 ? svlo : svhi) >> (i & 31)) & 1u;
      unsigned int kp = vi & (si ^ 1u) & 1u;
      kw |= ((unsigned long long)kp) << i;
      unsigned int tbv = ((i < 32 ? Tlo : Thi) >> (i & 31)) & 1u;
      supb |= tbv & kp;
    }
    if (lane == 0) keepw[b * NWIN + w] = kw;
    // phase 2: OR kept rows into suppressed mask, 16-deep batches
    int base = w * 64;
    unsigned long long kc = kw;
    while (kc) {
      int idx[PB];
#pragma unroll
      for (int t2 = 0; t2 < PB; t2++) idx[t2] = -1;
      for (int t2 = 0; t2 < PB; t2++) {
        if (!kc) break;
        idx[t2] = __ffsll((long long)kc) - 1;
        kc &= kc - 1;
      }
      uint4 q[PB];
#pragma unroll
      for (int t2 = 0; t2 < PB; t2++) {
        int ri = (idx[t2] >= 0) ? idx[t2] : idx[0];
        const uint4* rp = (const uint4*)(mb + (size_t)(base + ri) * NWORDS);
        q[t2] = (lane < 37) ? rp[lane] : make_uint4(0u, 0u, 0u, 0u);
      }
#pragma unroll
      for (int t2 = 0; t2 < PB; t2++) {
        unsigned long long m = (idx[t2] >= 0) ? ~0ull : 0ull;
        rw0 |= (((unsigned long long)q[t2].x) | (((unsigned long long)q[t2].y) << 32)) & m;
        rw1 |= (((unsigned long long)q[t2].z) | (((unsigned long long)q[t2].w) << 32)) & m;
      }
    }
    T = Tn; sval = svaln;
  }
}

// ---------------- final outputs ----------------
__global__ void k_out(const float* __restrict__ ss, const uint32_t* __restrict__ sl,
                      const float* __restrict__ sb, const unsigned long long* __restrict__ keepw,
                      float* __restrict__ out) {
  int r = blockIdx.x * blockDim.x + threadIdx.x;
  if (r >= BN * KTOT) return;
  int b = r / KTOT;
  int e = r - b * KTOT;
  unsigned int kp = (unsigned int)((keepw[b * NWIN + (e >> 6)] >> (e & 63)) & 1ull);
  out[(size_t)r * 5 + 0] = sb[(size_t)r * 4 + 0];
  out[(size_t)r * 5 + 1] = sb[(size_t)r * 4 + 1];
  out[(size_t)r * 5 + 2] = sb[(size_t)r * 4 + 2];
  out[(size_t)r * 5 + 3] = sb[(size_t)r * 4 + 3];
  out[(size_t)r * 5 + 4] = ss[r];
  out[(size_t)BN * KTOT * 5 + r] = (float)sl[r];
  out[(size_t)BN * KTOT * 6 + r] = kp ? 1.0f : 0.0f;
}

extern "C" void kernel_launch(void* const* d_in, const int* in_sizes, int n_in,
                              void* d_out, int out_size, void* d_ws, size_t ws_size,
                              hipStream_t stream) {
  InPtrs ip;
  for (int l = 0; l < 5; l++) {
    ip.cls[l]  = (const float*)d_in[3 * l + 0];
    ip.bbox[l] = (const float*)d_in[3 * l + 1];
    ip.ctr[l]  = (const float*)d_in[3 * l + 2];
  }

  size_t off = 0;
  auto alloc = [&](size_t n) {
    char* p = (char*)d_ws + off;
    off = (off + n + 255) & ~(size_t)255;
    return p;
  };
  const size_t SU_BYTES   = (size_t)BN * TOT * 4;           // 2.73 MB
  const size_t HIST_BYTES = 20ull * 65536 * 4;              // 5.24 MB
  const size_t MASK_BYTES = (size_t)BN * KTOT * NWORDS * 8; // 11.18 MB
  size_t region0 = ((SU_BYTES + 255) & ~(size_t)255) + HIST_BYTES;
  if (MASK_BYTES > region0) region0 = MASK_BYTES;
  char* r0p = (char*)alloc(region0);
  uint32_t* su   = (uint32_t*)r0p;
  uint32_t* hist = (uint32_t*)(r0p + ((SU_BYTES + 255) & ~(size_t)255));
  unsigned long long* mask = (unsigned long long*)r0p;

  uint32_t* mpfx   = (uint32_t*)alloc(20 * 4);
  uint32_t* mk     = (uint32_t*)alloc(20 * 4);
  uint32_t* selcnt = (uint32_t*)alloc(20 * 4);
  uint32_t* tiecnt = (uint32_t*)alloc(20 * 4);
  uint32_t* maxcb  = (uint32_t*)alloc(BN * 4);
  uint32_t* selu   = (uint32_t*)alloc(20ull * 1024 * 4);
  uint32_t* seli   = (uint32_t*)alloc(20ull * 1024 * 4);
  uint32_t* tiei   = (uint32_t*)alloc(20ull * TIE_CAP * 4);
  float*    ccs    = (float*)   alloc((size_t)BN * KTOT * 4);
  uint32_t* ccl    = (uint32_t*)alloc((size_t)BN * KTOT * 4);
  uint32_t* ccv    = (uint32_t*)alloc((size_t)BN * KTOT * 4);
  float*    ccb    = (float*)   alloc((size_t)BN * KTOT * 16);
  float*    ss     = (float*)   alloc((size_t)BN * KTOT * 4);
  uint32_t* sl     = (uint32_t*)alloc((size_t)BN * KTOT * 4);
  uint32_t* sv     = (uint32_t*)alloc((size_t)BN * KTOT * 4);
  float*    sb     = (float*)   alloc((size_t)BN * KTOT * 16);
  float*    ob     = (float*)   alloc((size_t)BN * KTOT * 16);
  unsigned long long* tdiag = (unsigned long long*)alloc((size_t)BN * NWIN * 64 * 8); // 148 KB
  unsigned long long* vbits = (unsigned long long*)alloc((size_t)BN * NWIN * 8);
  unsigned long long* keepw = (unsigned long long*)alloc((size_t)BN * NWIN * 8);
  (void)ws_size; (void)in_sizes; (void)n_in; (void)out_size;

  k_init<<<1, 64, 0, stream>>>(mk, mpfx, selcnt, tiecnt, maxcb);

  dim3 gscan((TOT + 255) / 256, BN);
  k_score<<<gscan, 256, 0, stream>>>(ip, su);
  for (int pass = 0; pass < 2; pass++) {
    hipMemsetAsync(hist, 0, HIST_BYTES, stream);
    k_histp<<<gscan, 256, 0, stream>>>(su, mpfx, hist, pass);
    k_findp<<<20, 1024, 0, stream>>>(hist, mpfx, mk, pass);
  }
  k_compact<<<gscan, 256, 0, stream>>>(su, mpfx, selcnt, tiecnt, selu, seli, tiei);
  k_ties<<<20, 256, 0, stream>>>(mpfx, mk, tiecnt, tiei, selu, seli);
  k_emit<<<20, 1024, 0, stream>>>(ip, selu, seli, ccs, ccl, ccv, ccb);
  k_sortimg<<<dim3(5, BN), 1024, 0, stream>>>(ccs, ccl, ccv, ccb, ss, sl, sv, sb, maxcb);
  k_bits<<<dim3(NWIN, BN), 64, 0, stream>>>(sv, vbits);
  k_offset<<<(BN * KTOT + 255) / 256, 256, 0, stream>>>(sb, sl, maxcb, ob);
  k_mask<<<dim3(19, BN), 256, 0, stream>>>(ob, mask, tdiag);
  k_nms<<<BN, 64, 0, stream>>>(mask, tdiag, vbits, keepw);
  k_out<<<(BN * KTOT + 255) / 256, 256, 0, stream>>>(ss, sl, sb, keepw, (float*)d_out);
}

// Round 9
// 1436.300 us; speedup vs baseline: 2.3487x; 1.5153x over previous
//
#include <hip/hip_runtime.h>
#include <stdint.h>

// FCOS bbox post-processing, B=4 images — bit-exact np/XLA-f32 replication
// (R7 semantics). R9: parallelism fixes.
//  - k_mask: 2D-tiled grid (19 x 5 x B); skips lower-triangle + diagonal mask
//    words (never read by k_nms: word w is consumed before window-w rows are
//    OR'd into the suppressed set). ~10x more blocks, ~2x less work.
//  - k_sortimg: 76 blocks x 256 thr (was 20 x 1024) — spreads LDS-pipe load.
//  - k_emit: packed u64 rank keys ((u<<32)|~idx, order-isomorphic to the
//    stable comparator), 80 blocks x 256 thr.
//  - k_nms: R8 blocked greedy (readlane diagonal scan + batched row ORs).

#define BN 4
#define NC 80
#define TOT 170720       // 128000+32000+8000+2000+720
#define KTOT 4720        // 1000*4+720
#define NWORDS 74        // ceil(4720/64)
#define NWIN 74
#define TIE_CAP 4096
#define IMGSZ 320.0f
#define PB 16            // k_nms phase-2 row-fetch batch

struct InPtrs {
  const float* cls[5];
  const float* bbox[5];
  const float* ctr[5];
};

__device__ __forceinline__ uint32_t f2s(float f) {
  uint32_t x = __float_as_uint(f);
  return (x & 0x80000000u) ? ~x : (x | 0x80000000u);
}
__device__ __forceinline__ float s2f(uint32_t s) {
  uint32_t x = (s & 0x80000000u) ? (s & 0x7fffffffu) : ~s;
  return __uint_as_float(x);
}
// np/XLA logistic: 1/(1+exp(-x)) with per-op f32 rounding.
__device__ __forceinline__ float sigmoid32(float v) {
  float e = (float)exp(-(double)v);          // CR f32 exp(-v)
  return __fdiv_rn(1.0f, __fadd_rn(1.0f, e));
}
__device__ __forceinline__ void lvl_of(int e, int& l, int& le) {
  if (e < 128000)      { l = 0; le = e; }
  else if (e < 160000) { l = 1; le = e - 128000; }
  else if (e < 168000) { l = 2; le = e - 160000; }
  else if (e < 170000) { l = 3; le = e - 168000; }
  else                 { l = 4; le = e - 170000; }
}
__device__ __forceinline__ int kl_of(int l) {
  constexpr int KL[5] = {1000, 1000, 1000, 1000, 720};
  return KL[l];
}
__device__ __forceinline__ float clip32(float v) {
  return fminf(fmaxf(v, 0.0f), IMGSZ);
}
// IoU > 0.5 predicate, exact np f32 op chain (identical to R7/R8).
__device__ __forceinline__ int iou_gt(float bx1, float by1, float bx2, float by2,
                                      float bai, float4 o) {
  float ta_ = __fmul_rn(__fsub_rn(o.z, o.x), __fsub_rn(o.w, o.y));
  float ltx = fmaxf(bx1, o.x), lty = fmaxf(by1, o.y);
  float rbx = fminf(bx2, o.z), rby = fminf(by2, o.w);
  float wd = fmaxf(__fsub_rn(rbx, ltx), 0.0f);
  float hg = fmaxf(__fsub_rn(rby, lty), 0.0f);
  float inter = __fmul_rn(wd, hg);
  float asum = __fadd_rn(bai, ta_);
  float uni  = __fsub_rn(asum, inter);
  float iou  = (uni > 0.0f) ? __fdiv_rn(inter, uni) : 0.0f;
  return (iou > 0.5f) ? 1 : 0;
}

// ---------------- init state ----------------
__global__ void k_init(uint32_t* __restrict__ mk, uint32_t* __restrict__ mpfx,
                       uint32_t* __restrict__ selcnt, uint32_t* __restrict__ tiecnt,
                       uint32_t* __restrict__ maxcb) {
  int t = threadIdx.x;
  if (t < 20) {
    mk[t] = (uint32_t)kl_of(t % 5);
    mpfx[t] = 0u;
    selcnt[t] = 0u;
    tiecnt[t] = 0u;
  }
  if (t < BN) maxcb[t] = 0u;
}

// ---------------- scores -> sortable u32 keys ----------------
__global__ void k_score(InPtrs in, uint32_t* __restrict__ su) {
  int b = blockIdx.y;
  int e = blockIdx.x * blockDim.x + threadIdx.x;
  if (e >= TOT) return;
  int l, le; lvl_of(e, l, le);
  constexpr int HWc[5] = {1600, 400, 100, 25, 9};
  int hw = HWc[l];
  int c = le % NC, p = le / NC;
  float v = in.cls[l][((size_t)b * NC + c) * hw + p];
  float s = sigmoid32(v);
  float m = (s > 0.025f) ? s : -1.0f;
  su[(size_t)b * TOT + e] = f2s(m);
}

// ---------------- radix pass (16-bit digits, 2 passes) ----------------
__global__ void k_histp(const uint32_t* __restrict__ su, const uint32_t* __restrict__ mpfx,
                        uint32_t* __restrict__ hist, int pass) {
  int b = blockIdx.y;
  int e = blockIdx.x * blockDim.x + threadIdx.x;
  if (e >= TOT) return;
  int l, le; lvl_of(e, l, le);
  int bl = b * 5 + l;
  uint32_t key = su[(size_t)b * TOT + e];
  bool match = (pass == 0) ? true : ((key >> 16) == (mpfx[bl] >> 16));
  if (match) {
    uint32_t digit = (pass == 0) ? (key >> 16) : (key & 0xFFFFu);
    bool neg = (key == 0x407FFFFFu) && ((e & ~63) != 169984);
    if (neg) {
      unsigned long long mb2 = __ballot(1);
      int lead = __ffsll((long long)mb2) - 1;
      if ((threadIdx.x & 63) == lead)
        atomicAdd(&hist[(size_t)bl * 65536u + digit], (uint32_t)__popcll(mb2));
    } else {
      atomicAdd(&hist[(size_t)bl * 65536u + digit], 1u);
    }
  }
}

__global__ void k_findp(const uint32_t* __restrict__ hist, uint32_t* __restrict__ mpfx,
                        uint32_t* __restrict__ mk, int pass) {
  int bl = blockIdx.x;
  uint32_t k = mk[bl];
  uint32_t pfx = mpfx[bl];
  const uint32_t* h = hist + (size_t)bl * 65536;
  __shared__ uint32_t sh[1024];
  int tid = threadIdx.x;
  int base = tid * 64;
  uint32_t s = 0;
  for (int i = 0; i < 64; i++) s += h[base + i];
  sh[tid] = s;
  __syncthreads();
  uint32_t above = 0;
  for (int t = tid + 1; t < 1024; t++) above += sh[t];
  if (above < k && above + s >= k) {
    uint32_t cum = above;
    for (int bin = base + 63; bin >= base; bin--) {
      uint32_t c = h[bin];
      if (cum < k && cum + c >= k) {
        if (pass == 0) mpfx[bl] = (uint32_t)bin << 16;
        else           mpfx[bl] = pfx | (uint32_t)bin;
        mk[bl] = k - cum;
        break;
      }
      cum += c;
    }
  }
}

// ---------------- compact selected ----------------
__global__ void k_compact(const uint32_t* __restrict__ su, const uint32_t* __restrict__ mpfx,
                          uint32_t* __restrict__ selcnt, uint32_t* __restrict__ tiecnt,
                          uint32_t* __restrict__ selu, uint32_t* __restrict__ seli,
                          uint32_t* __restrict__ tiei) {
  int b = blockIdx.y;
  int e = blockIdx.x * blockDim.x + threadIdx.x;
  if (e >= TOT) return;
  int l, le; lvl_of(e, l, le);
  int bl = b * 5 + l;
  uint32_t u = su[(size_t)b * TOT + e];
  uint32_t C = mpfx[bl];
  if (u > C) {
    uint32_t pos = atomicAdd(&selcnt[bl], 1u);
    selu[(size_t)bl * 1024 + pos] = u;
    seli[(size_t)bl * 1024 + pos] = (uint32_t)le;
  } else if (u == C) {
    uint32_t pos = atomicAdd(&tiecnt[bl], 1u);
    if (pos < TIE_CAP) tiei[(size_t)bl * TIE_CAP + pos] = (uint32_t)le;
  }
}

// Boundary ties: stable top_k -> smallest indices first.
__global__ void k_ties(const uint32_t* __restrict__ mpfx, const uint32_t* __restrict__ mk,
                       const uint32_t* __restrict__ tiecnt, const uint32_t* __restrict__ tiei,
                       uint32_t* __restrict__ selu, uint32_t* __restrict__ seli) {
  int bl = blockIdx.x;
  int l = bl % 5;
  uint32_t C = mpfx[bl];
  uint32_t T = mk[bl];
  uint32_t G = (uint32_t)kl_of(l) - T;
  uint32_t Tc = tiecnt[bl];
  if (Tc > TIE_CAP) Tc = TIE_CAP;
  __shared__ uint32_t sh[TIE_CAP];
  for (uint32_t t = threadIdx.x; t < Tc; t += blockDim.x) sh[t] = tiei[(size_t)bl * TIE_CAP + t];
  __syncthreads();
  for (uint32_t t = threadIdx.x; t < Tc; t += blockDim.x) {
    uint32_t my = sh[t];
    uint32_t rank = 0;
    for (uint32_t q = 0; q < Tc; q++) rank += (sh[q] < my) ? 1u : 0u;
    if (rank < T) {
      selu[(size_t)bl * 1024 + G + rank] = C;
      seli[(size_t)bl * 1024 + G + rank] = my;
    }
  }
}

// ---------------- exact rank within level + emit (packed u64 keys) --------------
// z = (u<<32)|~idx: z_j > z_i  <=>  (u_j>u_i) || (u_j==u_i && idx_j<idx_i).
__global__ void k_emit(InPtrs in, const uint32_t* __restrict__ selu, const uint32_t* __restrict__ seli,
                       float* __restrict__ ccs, uint32_t* __restrict__ ccl,
                       uint32_t* __restrict__ ccv, float* __restrict__ ccb) {
  int bl = blockIdx.x;
  int chunk = blockIdx.y;
  int b = bl / 5, l = bl % 5;
  int k = kl_of(l);
  __shared__ uint64_t z[1024];   // 8 KB
  int tid = threadIdx.x;
  for (int t = tid; t < 1024; t += 256) {
    if (t < k) {
      uint32_t u = selu[(size_t)bl * 1024 + t];
      uint32_t idx = seli[(size_t)bl * 1024 + t];
      z[t] = (((uint64_t)u) << 32) | (uint32_t)(~idx);
    } else z[t] = 0ull;
  }
  __syncthreads();
  int tg = chunk * 256 + tid;
  if (tg >= k) return;
  uint64_t zi = z[tg];
  uint32_t u = (uint32_t)(zi >> 32);
  uint32_t idx = ~(uint32_t)zi;
  int rank = 0;
  const uint4* z4 = (const uint4*)z;
  for (int j4 = 0; j4 < 512; j4++) {    // 2 u64 keys per b128 read; pads are 0
    uint4 q = z4[j4];
    uint64_t za = (((uint64_t)q.y) << 32) | q.x;
    uint64_t zb = (((uint64_t)q.w) << 32) | q.z;
    rank += (za > zi) ? 1 : 0;
    rank += (zb > zi) ? 1 : 0;
  }
  constexpr int Wc[5]  = {40, 20, 10, 5, 3};
  constexpr int HWc[5] = {1600, 400, 100, 25, 9};
  constexpr float Sc[5] = {8.f, 16.f, 32.f, 64.f, 128.f};
  constexpr int COFF[5] = {0, 1000, 2000, 3000, 4000};
  int w = Wc[l], hw = HWc[l];
  float ms = s2f(u);
  int valid = (ms > 0.025f) ? 1 : 0;
  int p = (int)idx / NC, c = (int)idx % NC;
  int x = p % w, y = p / w;
  float sf = sigmoid32(in.ctr[l][(size_t)b * hw + p]);
  float score = valid ? __fmul_rn(ms, sf) : -1.0f;
  float px = __fmul_rn(__fadd_rn((float)x, 0.5f), Sc[l]);
  float py = __fmul_rn(__fadd_rn((float)y, 0.5f), Sc[l]);
  size_t bb = (size_t)b * 4 * hw;
  float d0 = in.bbox[l][bb + 0 * hw + p];
  float d1 = in.bbox[l][bb + 1 * hw + p];
  float d2 = in.bbox[l][bb + 2 * hw + p];
  float d3 = in.bbox[l][bb + 3 * hw + p];
  float x1 = clip32(__fsub_rn(px, d0)), y1 = clip32(__fsub_rn(py, d1));
  float x2 = clip32(__fadd_rn(px, d2)), y2 = clip32(__fadd_rn(py, d3));
  int o = b * KTOT + COFF[l] + rank;
  ccs[o] = score;
  ccl[o] = (uint32_t)c;
  ccv[o] = (uint32_t)valid;
  ccb[(size_t)o * 4 + 0] = x1; ccb[(size_t)o * 4 + 1] = y1;
  ccb[(size_t)o * 4 + 2] = x2; ccb[(size_t)o * 4 + 3] = y2;
}

// ---------------- per-image stable descending sort (rank method) ----------------
__global__ void k_sortimg(const float* __restrict__ ccs, const uint32_t* __restrict__ ccl,
                          const uint32_t* __restrict__ ccv, const float* __restrict__ ccb,
                          float* __restrict__ ss, uint32_t* __restrict__ sl,
                          uint32_t* __restrict__ sv, float* __restrict__ sb,
                          uint32_t* __restrict__ maxcb) {
  int b = blockIdx.y;
  __shared__ uint32_t key[KTOT];   // 18.9 KB
  int tid = threadIdx.x;
  for (int e = tid; e < KTOT; e += 256) key[e] = f2s(ccs[(size_t)b * KTOT + e]);
  __syncthreads();
  int e = blockIdx.x * 256 + tid;
  if (e >= KTOT) return;
  uint32_t ke = key[e];
  int rank = 0;
  const uint4* k4 = (const uint4*)key;
  for (int j4 = 0; j4 < KTOT / 4; j4++) {
    uint4 kk = k4[j4];
    int j = j4 * 4;
    rank += ((kk.x > ke) || (kk.x == ke && (j + 0) < e)) ? 1 : 0;
    rank += ((kk.y > ke) || (kk.y == ke && (j + 1) < e)) ? 1 : 0;
    rank += ((kk.z > ke) || (kk.z == ke && (j + 2) < e)) ? 1 : 0;
    rank += ((kk.w > ke) || (kk.w == ke && (j + 3) < e)) ? 1 : 0;
  }
  int sidx = b * KTOT + e;
  int d = b * KTOT + rank;
  ss[d] = ccs[sidx];
  sl[d] = ccl[sidx];
  sv[d] = ccv[sidx];
  float b0 = ccb[(size_t)sidx * 4 + 0], b1 = ccb[(size_t)sidx * 4 + 1];
  float b2 = ccb[(size_t)sidx * 4 + 2], b3 = ccb[(size_t)sidx * 4 + 3];
  sb[(size_t)d * 4 + 0] = b0; sb[(size_t)d * 4 + 1] = b1;
  sb[(size_t)d * 4 + 2] = b2; sb[(size_t)d * 4 + 3] = b3;
  float mx = fmaxf(fmaxf(b0, b1), fmaxf(b2, b3));
  atomicMax(&maxcb[b], __float_as_uint(mx));
}

// ---------------- valid bits -> bitmask words ----------------
__global__ void k_bits(const uint32_t* __restrict__ sv, unsigned long long* __restrict__ vbits) {
  int w = blockIdx.x, b = blockIdx.y, lane = threadIdx.x;
  int e = w * 64 + lane;
  int pred = (e < KTOT) ? (sv[(size_t)b * KTOT + e] != 0u) : 0;
  unsigned long long m = __ballot(pred);
  if (lane == 0) vbits[b * NWIN + w] = m;
}

// ---------------- per-class offset boxes (f32) ----------------
__global__ void k_offset(const float* __restrict__ sb, const uint32_t* __restrict__ sl,
                         const uint32_t* __restrict__ maxcb, float* __restrict__ ob) {
  int r = blockIdx.x * blockDim.x + threadIdx.x;
  if (r >= BN * KTOT) return;
  int b = r / KTOT;
  float scale = __fadd_rn(__uint_as_float(maxcb[b]), 1.0f);
  float offv = __fmul_rn((float)sl[r], scale);
  float x1 = __fadd_rn(sb[(size_t)r * 4 + 0], offv);
  float y1 = __fadd_rn(sb[(size_t)r * 4 + 1], offv);
  float x2 = __fadd_rn(sb[(size_t)r * 4 + 2], offv);
  float y2 = __fadd_rn(sb[(size_t)r * 4 + 3], offv);
  ob[(size_t)r * 4 + 0] = x1; ob[(size_t)r * 4 + 1] = y1;
  ob[(size_t)r * 4 + 2] = x2; ob[(size_t)r * 4 + 3] = y2;
}

// ---------------- IoU bitmask, 2D-tiled ----------------
// Grid (19 i-chunks, 5 j-tiles, B). Words with gw <= myw are NEVER read by
// k_nms (word w is shfl-consumed before window-w rows are OR'd) -> skipped.
// Diagonal word computed only for the transposed tdiag blocks.
__global__ void k_mask(const float* __restrict__ ob, unsigned long long* __restrict__ mask,
                       unsigned long long* __restrict__ tdiag) {
  int b = blockIdx.z;
  int jt = blockIdx.y;
  int ib = blockIdx.x;
  int jbase = jt * 1024;
  int cnt = min(1024, KTOT - jbase);
  bool diagBlock = (jt == (ib >> 2));   // block's 4 i-windows live in tile ib>>2
  if (!diagBlock && (jbase + cnt - 1 <= ib * 256)) return;   // pure lower triangle
  __shared__ float4 tb[1024];   // 16 KB
  int tid = threadIdx.x;
  for (int j = tid; j < cnt; j += 256)
    tb[j] = ((const float4*)ob)[(size_t)b * KTOT + jbase + j];
  __syncthreads();
  int i = ib * 256 + tid;
  bool act = (i < KTOT);
  float bx1 = 0, by1 = 0, bx2 = 0, by2 = 0, bai = 0;
  if (act) {
    float4 v = ((const float4*)ob)[(size_t)b * KTOT + i];
    bx1 = v.x; by1 = v.y; bx2 = v.z; by2 = v.w;
    bai = __fmul_rn(__fsub_rn(bx2, bx1), __fsub_rn(by2, by1));
  }
  int myw = i >> 6;
  unsigned long long dw = 0ull;
  if (act) {
    unsigned long long* mrow = mask + ((size_t)b * KTOT + i) * NWORDS;
    int nw = (cnt + 63) >> 6;
    for (int w = 0; w < nw; w++) {
      int gw = jt * 16 + w;
      if (gw < myw) continue;
      unsigned long long bits = 0ull;
      int j0 = w * 64;
      int jn = min(64, cnt - j0);
      if (gw == myw) {          // diagonal word: only for tdiag capture
        for (int jj = 0; jj < jn; jj++) {
          if (jbase + j0 + jj > i)
            bits |= ((unsigned long long)iou_gt(bx1, by1, bx2, by2, bai, tb[j0 + jj])) << jj;
        }
        dw = bits;              // no global write (never read from mask)
      } else {                  // strictly upper: all j > i
        for (int jj = 0; jj < jn; jj++)
          bits |= ((unsigned long long)iou_gt(bx1, by1, bx2, by2, bai, tb[j0 + jj])) << jj;
        mrow[gw] = bits;
      }
    }
  }
  if (diagBlock) {              // block-uniform; transpose 64x64 diag per wave
    int lane = tid & 63;
    unsigned long long col = 0ull;
#pragma unroll
    for (int j = 0; j < 64; j++) {
      unsigned long long bal = __ballot((int)((dw >> j) & 1ull));
      if (lane == j) col = bal;
    }
    if (myw < NWIN) tdiag[((size_t)b * NWIN + (size_t)myw) * 64 + lane] = col;
  }
}

// ---------------- blocked greedy NMS, one wave per image ----------------
__global__ void k_nms(const unsigned long long* __restrict__ mask,
                      const unsigned long long* __restrict__ tdiag,
                      const unsigned long long* __restrict__ vbits,
                      unsigned long long* __restrict__ keepw) {
  int b = blockIdx.x;
  int lane = threadIdx.x;
  const unsigned long long* mb = mask + (size_t)b * KTOT * NWORDS;
  unsigned long long rw0 = 0ull, rw1 = 0ull;   // suppressed words 2*lane, 2*lane+1
  unsigned long long T = tdiag[((size_t)b * NWIN + 0) * 64 + lane];
  unsigned long long sval = vbits[b * NWIN + 0];
  for (int w = 0; w < NWIN; w++) {
    unsigned long long Tn = 0ull, svaln = 0ull;
    if (w + 1 < NWIN) {
      Tn = tdiag[((size_t)b * NWIN + (w + 1)) * 64 + lane];
      svaln = vbits[b * NWIN + (w + 1)];
    }
    int lsrc = w >> 1;
    unsigned long long sa = __shfl(rw0, lsrc, 64);
    unsigned long long sb2 = __shfl(rw1, lsrc, 64);
    unsigned long long s_in = (w & 1) ? sb2 : sa;
    unsigned int supb = (unsigned int)((s_in >> lane) & 1ull);
    unsigned int Tlo = (unsigned int)T, Thi = (unsigned int)(T >> 32);
    unsigned int svlo = (unsigned int)sval, svhi = (unsigned int)(sval >> 32);
    unsigned long long kw = 0ull;
#pragma unroll
    for (int i = 0; i < 64; i++) {
      unsigned int si = (unsigned int)__builtin_amdgcn_readlane((int)supb, i);
      unsigned int vi = ((i < 32 ? svlo : svhi) >> (i & 31)) & 1u;
      unsigned int kp = vi & (si ^ 1u) & 1u;
      kw |= ((unsigned long long)kp) << i;
      unsigned int tbv = ((i < 32 ? Tlo : Thi) >> (i & 31)) & 1u;
      supb |= tbv & kp;
    }
    if (lane == 0) keepw[b * NWIN + w] = kw;
    int base = w * 64;
    unsigned long long kc = kw;
    while (kc) {
      int idx[PB];
#pragma unroll
      for (int t2 = 0; t2 < PB; t2++) idx[t2] = -1;
      for (int t2 = 0; t2 < PB; t2++) {
        if (!kc) break;
        idx[t2] = __ffsll((long long)kc) - 1;
        kc &= kc - 1;
      }
      uint4 q[PB];
#pragma unroll
      for (int t2 = 0; t2 < PB; t2++) {
        int ri = (idx[t2] >= 0) ? idx[t2] : idx[0];
        const uint4* rp = (const uint4*)(mb + (size_t)(base + ri) * NWORDS);
        q[t2] = (lane < 37) ? rp[lane] : make_uint4(0u, 0u, 0u, 0u);
      }
#pragma unroll
      for (int t2 = 0; t2 < PB; t2++) {
        unsigned long long m = (idx[t2] >= 0) ? ~0ull : 0ull;
        rw0 |= (((unsigned long long)q[t2].x) | (((unsigned long long)q[t2].y) << 32)) & m;
        rw1 |= (((unsigned long long)q[t2].z) | (((unsigned long long)q[t2].w) << 32)) & m;
      }
    }
    T = Tn; sval = svaln;
  }
}

// ---------------- final outputs ----------------
__global__ void k_out(const float* __restrict__ ss, const uint32_t* __restrict__ sl,
                      const float* __restrict__ sb, const unsigned long long* __restrict__ keepw,
                      float* __restrict__ out) {
  int r = blockIdx.x * blockDim.x + threadIdx.x;
  if (r >= BN * KTOT) return;
  int b = r / KTOT;
  int e = r - b * KTOT;
  unsigned int kp = (unsigned int)((keepw[b * NWIN + (e >> 6)] >> (e & 63)) & 1ull);
  out[(size_t)r * 5 + 0] = sb[(size_t)r * 4 + 0];
  out[(size_t)r * 5 + 1] = sb[(size_t)r * 4 + 1];
  out[(size_t)r * 5 + 2] = sb[(size_t)r * 4 + 2];
  out[(size_t)r * 5 + 3] = sb[(size_t)r * 4 + 3];
  out[(size_t)r * 5 + 4] = ss[r];
  out[(size_t)BN * KTOT * 5 + r] = (float)sl[r];
  out[(size_t)BN * KTOT * 6 + r] = kp ? 1.0f : 0.0f;
}

extern "C" void kernel_launch(void* const* d_in, const int* in_sizes, int n_in,
                              void* d_out, int out_size, void* d_ws, size_t ws_size,
                              hipStream_t stream) {
  InPtrs ip;
  for (int l = 0; l < 5; l++) {
    ip.cls[l]  = (const float*)d_in[3 * l + 0];
    ip.bbox[l] = (const float*)d_in[3 * l + 1];
    ip.ctr[l]  = (const float*)d_in[3 * l + 2];
  }

  size_t off = 0;
  auto alloc = [&](size_t n) {
    char* p = (char*)d_ws + off;
    off = (off + n + 255) & ~(size_t)255;
    return p;
  };
  const size_t SU_BYTES   = (size_t)BN * TOT * 4;           // 2.73 MB
  const size_t HIST_BYTES = 20ull * 65536 * 4;              // 5.24 MB
  const size_t MASK_BYTES = (size_t)BN * KTOT * NWORDS * 8; // 11.18 MB
  size_t region0 = ((SU_BYTES + 255) & ~(size_t)255) + HIST_BYTES;
  if (MASK_BYTES > region0) region0 = MASK_BYTES;
  char* r0p = (char*)alloc(region0);
  uint32_t* su   = (uint32_t*)r0p;
  uint32_t* hist = (uint32_t*)(r0p + ((SU_BYTES + 255) & ~(size_t)255));
  unsigned long long* mask = (unsigned long long*)r0p;

  uint32_t* mpfx   = (uint32_t*)alloc(20 * 4);
  uint32_t* mk     = (uint32_t*)alloc(20 * 4);
  uint32_t* selcnt = (uint32_t*)alloc(20 * 4);
  uint32_t* tiecnt = (uint32_t*)alloc(20 * 4);
  uint32_t* maxcb  = (uint32_t*)alloc(BN * 4);
  uint32_t* selu   = (uint32_t*)alloc(20ull * 1024 * 4);
  uint32_t* seli   = (uint32_t*)alloc(20ull * 1024 * 4);
  uint32_t* tiei   = (uint32_t*)alloc(20ull * TIE_CAP * 4);
  float*    ccs    = (float*)   alloc((size_t)BN * KTOT * 4);
  uint32_t* ccl    = (uint32_t*)alloc((size_t)BN * KTOT * 4);
  uint32_t* ccv    = (uint32_t*)alloc((size_t)BN * KTOT * 4);
  float*    ccb    = (float*)   alloc((size_t)BN * KTOT * 16);
  float*    ss     = (float*)   alloc((size_t)BN * KTOT * 4);
  uint32_t* sl     = (uint32_t*)alloc((size_t)BN * KTOT * 4);
  uint32_t* sv     = (uint32_t*)alloc((size_t)BN * KTOT * 4);
  float*    sb     = (float*)   alloc((size_t)BN * KTOT * 16);
  float*    ob     = (float*)   alloc((size_t)BN * KTOT * 16);
  unsigned long long* tdiag = (unsigned long long*)alloc((size_t)BN * NWIN * 64 * 8); // 148 KB
  unsigned long long* vbits = (unsigned long long*)alloc((size_t)BN * NWIN * 8);
  unsigned long long* keepw = (unsigned long long*)alloc((size_t)BN * NWIN * 8);
  (void)ws_size; (void)in_sizes; (void)n_in; (void)out_size;

  k_init<<<1, 64, 0, stream>>>(mk, mpfx, selcnt, tiecnt, maxcb);

  dim3 gscan((TOT + 255) / 256, BN);
  k_score<<<gscan, 256, 0, stream>>>(ip, su);
  for (int pass = 0; pass < 2; pass++) {
    hipMemsetAsync(hist, 0, HIST_BYTES, stream);
    k_histp<<<gscan, 256, 0, stream>>>(su, mpfx, hist, pass);
    k_findp<<<20, 1024, 0, stream>>>(hist, mpfx, mk, pass);
  }
  k_compact<<<gscan, 256, 0, stream>>>(su, mpfx, selcnt, tiecnt, selu, seli, tiei);
  k_ties<<<20, 256, 0, stream>>>(mpfx, mk, tiecnt, tiei, selu, seli);
  k_emit<<<dim3(20, 4), 256, 0, stream>>>(ip, selu, seli, ccs, ccl, ccv, ccb);
  k_sortimg<<<dim3(19, BN), 256, 0, stream>>>(ccs, ccl, ccv, ccb, ss, sl, sv, sb, maxcb);
  k_bits<<<dim3(NWIN, BN), 64, 0, stream>>>(sv, vbits);
  k_offset<<<(BN * KTOT + 255) / 256, 256, 0, stream>>>(sb, sl, maxcb, ob);
  k_mask<<<dim3(19, 5, BN), 256, 0, stream>>>(ob, mask, tdiag);
  k_nms<<<BN, 64, 0, stream>>>(mask, tdiag, vbits, keepw);
  k_out<<<(BN * KTOT + 255) / 256, 256, 0, stream>>>(ss, sl, sb, keepw, (float*)d_out);
}

// Round 10
// 1252.847 us; speedup vs baseline: 2.6926x; 1.1464x over previous
//
#include <hip/hip_runtime.h>
#include <stdint.h>

// FCOS bbox post-processing, B=4 images — bit-exact np/XLA-f32 replication
// (R7 semantics). R10: pipelined LDS-staged k_nms.
//  - k_nms: 256-thread block per image; speculative full-window row prefetch
//    (regs -> LDS double buffer), wave-0 readlane diagonal scan, 74
//    owner-thread conflict-free OR phase. 1-window software pipeline hides
//    the row-fetch latency that dominated R9 (680 us).
//  - everything else identical to R9 (bit-exact chains).

#define BN 4
#define NC 80
#define TOT 170720       // 128000+32000+8000+2000+720
#define KTOT 4720        // 1000*4+720
#define NWORDS 74        // ceil(4720/64)
#define NWIN 74
#define TIE_CAP 4096
#define IMGSZ 320.0f
#define WCH 2368         // uint4 chunks per 64-row window (64*74*8/16)

struct InPtrs {
  const float* cls[5];
  const float* bbox[5];
  const float* ctr[5];
};

__device__ __forceinline__ uint32_t f2s(float f) {
  uint32_t x = __float_as_uint(f);
  return (x & 0x80000000u) ? ~x : (x | 0x80000000u);
}
__device__ __forceinline__ float s2f(uint32_t s) {
  uint32_t x = (s & 0x80000000u) ? (s & 0x7fffffffu) : ~s;
  return __uint_as_float(x);
}
// np/XLA logistic: 1/(1+exp(-x)) with per-op f32 rounding.
__device__ __forceinline__ float sigmoid32(float v) {
  float e = (float)exp(-(double)v);          // CR f32 exp(-v)
  return __fdiv_rn(1.0f, __fadd_rn(1.0f, e));
}
__device__ __forceinline__ void lvl_of(int e, int& l, int& le) {
  if (e < 128000)      { l = 0; le = e; }
  else if (e < 160000) { l = 1; le = e - 128000; }
  else if (e < 168000) { l = 2; le = e - 160000; }
  else if (e < 170000) { l = 3; le = e - 168000; }
  else                 { l = 4; le = e - 170000; }
}
__device__ __forceinline__ int kl_of(int l) {
  constexpr int KL[5] = {1000, 1000, 1000, 1000, 720};
  return KL[l];
}
__device__ __forceinline__ float clip32(float v) {
  return fminf(fmaxf(v, 0.0f), IMGSZ);
}
// IoU > 0.5 predicate, exact np f32 op chain (identical to R7/R8/R9).
__device__ __forceinline__ int iou_gt(float bx1, float by1, float bx2, float by2,
                                      float bai, float4 o) {
  float ta_ = __fmul_rn(__fsub_rn(o.z, o.x), __fsub_rn(o.w, o.y));
  float ltx = fmaxf(bx1, o.x), lty = fmaxf(by1, o.y);
  float rbx = fminf(bx2, o.z), rby = fminf(by2, o.w);
  float wd = fmaxf(__fsub_rn(rbx, ltx), 0.0f);
  float hg = fmaxf(__fsub_rn(rby, lty), 0.0f);
  float inter = __fmul_rn(wd, hg);
  float asum = __fadd_rn(bai, ta_);
  float uni  = __fsub_rn(asum, inter);
  float iou  = (uni > 0.0f) ? __fdiv_rn(inter, uni) : 0.0f;
  return (iou > 0.5f) ? 1 : 0;
}

// ---------------- init state ----------------
__global__ void k_init(uint32_t* __restrict__ mk, uint32_t* __restrict__ mpfx,
                       uint32_t* __restrict__ selcnt, uint32_t* __restrict__ tiecnt,
                       uint32_t* __restrict__ maxcb) {
  int t = threadIdx.x;
  if (t < 20) {
    mk[t] = (uint32_t)kl_of(t % 5);
    mpfx[t] = 0u;
    selcnt[t] = 0u;
    tiecnt[t] = 0u;
  }
  if (t < BN) maxcb[t] = 0u;
}

// ---------------- scores -> sortable u32 keys ----------------
__global__ void k_score(InPtrs in, uint32_t* __restrict__ su) {
  int b = blockIdx.y;
  int e = blockIdx.x * blockDim.x + threadIdx.x;
  if (e >= TOT) return;
  int l, le; lvl_of(e, l, le);
  constexpr int HWc[5] = {1600, 400, 100, 25, 9};
  int hw = HWc[l];
  int c = le % NC, p = le / NC;
  float v = in.cls[l][((size_t)b * NC + c) * hw + p];
  float s = sigmoid32(v);
  float m = (s > 0.025f) ? s : -1.0f;
  su[(size_t)b * TOT + e] = f2s(m);
}

// ---------------- radix pass (16-bit digits, 2 passes) ----------------
__global__ void k_histp(const uint32_t* __restrict__ su, const uint32_t* __restrict__ mpfx,
                        uint32_t* __restrict__ hist, int pass) {
  int b = blockIdx.y;
  int e = blockIdx.x * blockDim.x + threadIdx.x;
  if (e >= TOT) return;
  int l, le; lvl_of(e, l, le);
  int bl = b * 5 + l;
  uint32_t key = su[(size_t)b * TOT + e];
  bool match = (pass == 0) ? true : ((key >> 16) == (mpfx[bl] >> 16));
  if (match) {
    uint32_t digit = (pass == 0) ? (key >> 16) : (key & 0xFFFFu);
    bool neg = (key == 0x407FFFFFu) && ((e & ~63) != 169984);
    if (neg) {
      unsigned long long mb2 = __ballot(1);
      int lead = __ffsll((long long)mb2) - 1;
      if ((threadIdx.x & 63) == lead)
        atomicAdd(&hist[(size_t)bl * 65536u + digit], (uint32_t)__popcll(mb2));
    } else {
      atomicAdd(&hist[(size_t)bl * 65536u + digit], 1u);
    }
  }
}

__global__ void k_findp(const uint32_t* __restrict__ hist, uint32_t* __restrict__ mpfx,
                        uint32_t* __restrict__ mk, int pass) {
  int bl = blockIdx.x;
  uint32_t k = mk[bl];
  uint32_t pfx = mpfx[bl];
  const uint32_t* h = hist + (size_t)bl * 65536;
  __shared__ uint32_t sh[1024];
  int tid = threadIdx.x;
  int base = tid * 64;
  uint32_t s = 0;
  for (int i = 0; i < 64; i++) s += h[base + i];
  sh[tid] = s;
  __syncthreads();
  uint32_t above = 0;
  for (int t = tid + 1; t < 1024; t++) above += sh[t];
  if (above < k && above + s >= k) {
    uint32_t cum = above;
    for (int bin = base + 63; bin >= base; bin--) {
      uint32_t c = h[bin];
      if (cum < k && cum + c >= k) {
        if (pass == 0) mpfx[bl] = (uint32_t)bin << 16;
        else           mpfx[bl] = pfx | (uint32_t)bin;
        mk[bl] = k - cum;
        break;
      }
      cum += c;
    }
  }
}

// ---------------- compact selected ----------------
__global__ void k_compact(const uint32_t* __restrict__ su, const uint32_t* __restrict__ mpfx,
                          uint32_t* __restrict__ selcnt, uint32_t* __restrict__ tiecnt,
                          uint32_t* __restrict__ selu, uint32_t* __restrict__ seli,
                          uint32_t* __restrict__ tiei) {
  int b = blockIdx.y;
  int e = blockIdx.x * blockDim.x + threadIdx.x;
  if (e >= TOT) return;
  int l, le; lvl_of(e, l, le);
  int bl = b * 5 + l;
  uint32_t u = su[(size_t)b * TOT + e];
  uint32_t C = mpfx[bl];
  if (u > C) {
    uint32_t pos = atomicAdd(&selcnt[bl], 1u);
    selu[(size_t)bl * 1024 + pos] = u;
    seli[(size_t)bl * 1024 + pos] = (uint32_t)le;
  } else if (u == C) {
    uint32_t pos = atomicAdd(&tiecnt[bl], 1u);
    if (pos < TIE_CAP) tiei[(size_t)bl * TIE_CAP + pos] = (uint32_t)le;
  }
}

// Boundary ties: stable top_k -> smallest indices first.
__global__ void k_ties(const uint32_t* __restrict__ mpfx, const uint32_t* __restrict__ mk,
                       const uint32_t* __restrict__ tiecnt, const uint32_t* __restrict__ tiei,
                       uint32_t* __restrict__ selu, uint32_t* __restrict__ seli) {
  int bl = blockIdx.x;
  int l = bl % 5;
  uint32_t C = mpfx[bl];
  uint32_t T = mk[bl];
  uint32_t G = (uint32_t)kl_of(l) - T;
  uint32_t Tc = tiecnt[bl];
  if (Tc > TIE_CAP) Tc = TIE_CAP;
  __shared__ uint32_t sh[TIE_CAP];
  for (uint32_t t = threadIdx.x; t < Tc; t += blockDim.x) sh[t] = tiei[(size_t)bl * TIE_CAP + t];
  __syncthreads();
  for (uint32_t t = threadIdx.x; t < Tc; t += blockDim.x) {
    uint32_t my = sh[t];
    uint32_t rank = 0;
    for (uint32_t q = 0; q < Tc; q++) rank += (sh[q] < my) ? 1u : 0u;
    if (rank < T) {
      selu[(size_t)bl * 1024 + G + rank] = C;
      seli[(size_t)bl * 1024 + G + rank] = my;
    }
  }
}

// ---------------- exact rank within level + emit (packed u64 keys) --------------
__global__ void k_emit(InPtrs in, const uint32_t* __restrict__ selu, const uint32_t* __restrict__ seli,
                       float* __restrict__ ccs, uint32_t* __restrict__ ccl,
                       uint32_t* __restrict__ ccv, float* __restrict__ ccb) {
  int bl = blockIdx.x;
  int chunk = blockIdx.y;
  int b = bl / 5, l = bl % 5;
  int k = kl_of(l);
  __shared__ uint64_t z[1024];   // 8 KB
  int tid = threadIdx.x;
  for (int t = tid; t < 1024; t += 256) {
    if (t < k) {
      uint32_t u = selu[(size_t)bl * 1024 + t];
      uint32_t idx = seli[(size_t)bl * 1024 + t];
      z[t] = (((uint64_t)u) << 32) | (uint32_t)(~idx);
    } else z[t] = 0ull;
  }
  __syncthreads();
  int tg = chunk * 256 + tid;
  if (tg >= k) return;
  uint64_t zi = z[tg];
  uint32_t u = (uint32_t)(zi >> 32);
  uint32_t idx = ~(uint32_t)zi;
  int rank = 0;
  const uint4* z4 = (const uint4*)z;
  for (int j4 = 0; j4 < 512; j4++) {
    uint4 q = z4[j4];
    uint64_t za = (((uint64_t)q.y) << 32) | q.x;
    uint64_t zb = (((uint64_t)q.w) << 32) | q.z;
    rank += (za > zi) ? 1 : 0;
    rank += (zb > zi) ? 1 : 0;
  }
  constexpr int Wc[5]  = {40, 20, 10, 5, 3};
  constexpr int HWc[5] = {1600, 400, 100, 25, 9};
  constexpr float Sc[5] = {8.f, 16.f, 32.f, 64.f, 128.f};
  constexpr int COFF[5] = {0, 1000, 2000, 3000, 4000};
  int w = Wc[l], hw = HWc[l];
  float ms = s2f(u);
  int valid = (ms > 0.025f) ? 1 : 0;
  int p = (int)idx / NC, c = (int)idx % NC;
  int x = p % w, y = p / w;
  float sf = sigmoid32(in.ctr[l][(size_t)b * hw + p]);
  float score = valid ? __fmul_rn(ms, sf) : -1.0f;
  float px = __fmul_rn(__fadd_rn((float)x, 0.5f), Sc[l]);
  float py = __fmul_rn(__fadd_rn((float)y, 0.5f), Sc[l]);
  size_t bb = (size_t)b * 4 * hw;
  float d0 = in.bbox[l][bb + 0 * hw + p];
  float d1 = in.bbox[l][bb + 1 * hw + p];
  float d2 = in.bbox[l][bb + 2 * hw + p];
  float d3 = in.bbox[l][bb + 3 * hw + p];
  float x1 = clip32(__fsub_rn(px, d0)), y1 = clip32(__fsub_rn(py, d1));
  float x2 = clip32(__fadd_rn(px, d2)), y2 = clip32(__fadd_rn(py, d3));
  int o = b * KTOT + COFF[l] + rank;
  ccs[o] = score;
  ccl[o] = (uint32_t)c;
  ccv[o] = (uint32_t)valid;
  ccb[(size_t)o * 4 + 0] = x1; ccb[(size_t)o * 4 + 1] = y1;
  ccb[(size_t)o * 4 + 2] = x2; ccb[(size_t)o * 4 + 3] = y2;
}

// ---------------- per-image stable descending sort (rank method) ----------------
__global__ void k_sortimg(const float* __restrict__ ccs, const uint32_t* __restrict__ ccl,
                          const uint32_t* __restrict__ ccv, const float* __restrict__ ccb,
                          float* __restrict__ ss, uint32_t* __restrict__ sl,
                          uint32_t* __restrict__ sv, float* __restrict__ sb,
                          uint32_t* __restrict__ maxcb) {
  int b = blockIdx.y;
  __shared__ uint32_t key[KTOT];   // 18.9 KB
  int tid = threadIdx.x;
  for (int e = tid; e < KTOT; e += 256) key[e] = f2s(ccs[(size_t)b * KTOT + e]);
  __syncthreads();
  int e = blockIdx.x * 256 + tid;
  if (e >= KTOT) return;
  uint32_t ke = key[e];
  int rank = 0;
  const uint4* k4 = (const uint4*)key;
  for (int j4 = 0; j4 < KTOT / 4; j4++) {
    uint4 kk = k4[j4];
    int j = j4 * 4;
    rank += ((kk.x > ke) || (kk.x == ke && (j + 0) < e)) ? 1 : 0;
    rank += ((kk.y > ke) || (kk.y == ke && (j + 1) < e)) ? 1 : 0;
    rank += ((kk.z > ke) || (kk.z == ke && (j + 2) < e)) ? 1 : 0;
    rank += ((kk.w > ke) || (kk.w == ke && (j + 3) < e)) ? 1 : 0;
  }
  int sidx = b * KTOT + e;
  int d = b * KTOT + rank;
  ss[d] = ccs[sidx];
  sl[d] = ccl[sidx];
  sv[d] = ccv[sidx];
  float b0 = ccb[(size_t)sidx * 4 + 0], b1 = ccb[(size_t)sidx * 4 + 1];
  float b2 = ccb[(size_t)sidx * 4 + 2], b3 = ccb[(size_t)sidx * 4 + 3];
  sb[(size_t)d * 4 + 0] = b0; sb[(size_t)d * 4 + 1] = b1;
  sb[(size_t)d * 4 + 2] = b2; sb[(size_t)d * 4 + 3] = b3;
  float mx = fmaxf(fmaxf(b0, b1), fmaxf(b2, b3));
  atomicMax(&maxcb[b], __float_as_uint(mx));
}

// ---------------- valid bits -> bitmask words ----------------
__global__ void k_bits(const uint32_t* __restrict__ sv, unsigned long long* __restrict__ vbits) {
  int w = blockIdx.x, b = blockIdx.y, lane = threadIdx.x;
  int e = w * 64 + lane;
  int pred = (e < KTOT) ? (sv[(size_t)b * KTOT + e] != 0u) : 0;
  unsigned long long m = __ballot(pred);
  if (lane == 0) vbits[b * NWIN + w] = m;
}

// ---------------- per-class offset boxes (f32) ----------------
__global__ void k_offset(const float* __restrict__ sb, const uint32_t* __restrict__ sl,
                         const uint32_t* __restrict__ maxcb, float* __restrict__ ob) {
  int r = blockIdx.x * blockDim.x + threadIdx.x;
  if (r >= BN * KTOT) return;
  int b = r / KTOT;
  float scale = __fadd_rn(__uint_as_float(maxcb[b]), 1.0f);
  float offv = __fmul_rn((float)sl[r], scale);
  float x1 = __fadd_rn(sb[(size_t)r * 4 + 0], offv);
  float y1 = __fadd_rn(sb[(size_t)r * 4 + 1], offv);
  float x2 = __fadd_rn(sb[(size_t)r * 4 + 2], offv);
  float y2 = __fadd_rn(sb[(size_t)r * 4 + 3], offv);
  ob[(size_t)r * 4 + 0] = x1; ob[(size_t)r * 4 + 1] = y1;
  ob[(size_t)r * 4 + 2] = x2; ob[(size_t)r * 4 + 3] = y2;
}

// ---------------- IoU bitmask, 2D-tiled (R9) ----------------
__global__ void k_mask(const float* __restrict__ ob, unsigned long long* __restrict__ mask,
                       unsigned long long* __restrict__ tdiag) {
  int b = blockIdx.z;
  int jt = blockIdx.y;
  int ib = blockIdx.x;
  int jbase = jt * 1024;
  int cnt = min(1024, KTOT - jbase);
  bool diagBlock = (jt == (ib >> 2));
  if (!diagBlock && (jbase + cnt - 1 <= ib * 256)) return;
  __shared__ float4 tb[1024];   // 16 KB
  int tid = threadIdx.x;
  for (int j = tid; j < cnt; j += 256)
    tb[j] = ((const float4*)ob)[(size_t)b * KTOT + jbase + j];
  __syncthreads();
  int i = ib * 256 + tid;
  bool act = (i < KTOT);
  float bx1 = 0, by1 = 0, bx2 = 0, by2 = 0, bai = 0;
  if (act) {
    float4 v = ((const float4*)ob)[(size_t)b * KTOT + i];
    bx1 = v.x; by1 = v.y; bx2 = v.z; by2 = v.w;
    bai = __fmul_rn(__fsub_rn(bx2, bx1), __fsub_rn(by2, by1));
  }
  int myw = i >> 6;
  unsigned long long dw = 0ull;
  if (act) {
    unsigned long long* mrow = mask + ((size_t)b * (KTOT + 64) + i) * NWORDS;
    int nw = (cnt + 63) >> 6;
    for (int w = 0; w < nw; w++) {
      int gw = jt * 16 + w;
      if (gw < myw) continue;
      unsigned long long bits = 0ull;
      int j0 = w * 64;
      int jn = min(64, cnt - j0);
      if (gw == myw) {
        for (int jj = 0; jj < jn; jj++) {
          if (jbase + j0 + jj > i)
            bits |= ((unsigned long long)iou_gt(bx1, by1, bx2, by2, bai, tb[j0 + jj])) << jj;
        }
        dw = bits;
      } else {
        for (int jj = 0; jj < jn; jj++)
          bits |= ((unsigned long long)iou_gt(bx1, by1, bx2, by2, bai, tb[j0 + jj])) << jj;
        mrow[gw] = bits;
      }
    }
  }
  if (diagBlock) {
    int lane = tid & 63;
    unsigned long long col = 0ull;
#pragma unroll
    for (int j = 0; j < 64; j++) {
      unsigned long long bal = __ballot((int)((dw >> j) & 1ull));
      if (lane == j) col = bal;
    }
    if (myw < NWIN) tdiag[((size_t)b * NWIN + (size_t)myw) * 64 + lane] = col;
  }
}

// ---------------- pipelined blocked greedy NMS, one 256-thr block per image -----
// LDS: double-buffered 64-row window (2x37888 B) + suppressed mask (74 u64).
// Pipeline per window w: speculative register loads of window w+1; wave-0
// readlane diagonal scan (consumes sup[w]); owner-thread OR of window-w kept
// rows (already in LDS); register spill to the other LDS buffer.
__global__ void k_nms(const unsigned long long* __restrict__ mask,
                      const unsigned long long* __restrict__ tdiag,
                      const unsigned long long* __restrict__ vbits,
                      unsigned long long* __restrict__ keepw) {
  int b = blockIdx.x;
  int tid = threadIdx.x;
  int lane = tid & 63;
  int wv = tid >> 6;
  const unsigned long long* mb = mask + (size_t)b * (KTOT + 64) * NWORDS;
  __shared__ unsigned long long buf[2][64 * NWORDS];   // 75776 B
  __shared__ unsigned long long sup[NWIN];             // 592 B
  __shared__ unsigned long long kwsh;
  for (int t = tid; t < NWIN; t += 256) sup[t] = 0ull;
  // preload window 0 into buf[0]
  {
    const uint4* src4 = (const uint4*)mb;
    uint4* dst4 = (uint4*)&buf[0][0];
    for (int s = 0; s < 10; s++) {
      int c = tid + 256 * s;
      if (c < WCH) dst4[c] = src4[c];
    }
  }
  unsigned long long T = 0ull, sval = 0ull;
  if (wv == 0) {
    T = tdiag[((size_t)b * NWIN + 0) * 64 + lane];
    sval = vbits[b * NWIN + 0];
  }
  __syncthreads();
  for (int w = 0; w < NWIN; w++) {
    // 1) speculative loads of window w+1 (all threads) — consumed at step 4
    uint4 r[10];
    bool pf = (w + 1 < NWIN);
    if (pf) {
      const uint4* src4 = (const uint4*)(mb + (size_t)(w + 1) * 64 * NWORDS);
#pragma unroll
      for (int s = 0; s < 10; s++) {
        int c = tid + 256 * s;
        if (c < WCH) r[s] = src4[c];
      }
    }
    unsigned long long Tn = 0ull, svaln = 0ull;
    if (wv == 0 && pf) {
      Tn = tdiag[((size_t)b * NWIN + (w + 1)) * 64 + lane];
      svaln = vbits[b * NWIN + (w + 1)];
    }
    // 2) wave-0 diagonal scan
    if (wv == 0) {
      unsigned long long s_in = sup[w];
      unsigned int supb = (unsigned int)((s_in >> lane) & 1ull);
      unsigned int Tlo = (unsigned int)T, Thi = (unsigned int)(T >> 32);
      unsigned int svlo = (unsigned int)sval, svhi = (unsigned int)(sval >> 32);
      unsigned long long kw = 0ull;
#pragma unroll
      for (int i = 0; i < 64; i++) {
        unsigned int si = (unsigned int)__builtin_amdgcn_readlane((int)supb, i);
        unsigned int vi = ((i < 32 ? svlo : svhi) >> (i & 31)) & 1u;
        unsigned int kp = vi & (si ^ 1u) & 1u;
        kw |= ((unsigned long long)kp) << i;
        unsigned int tbv = ((i < 32 ? Tlo : Thi) >> (i & 31)) & 1u;
        supb |= tbv & kp;
      }
      if (lane == 0) {
        keepw[b * NWIN + w] = kw;
        kwsh = kw;
      }
      T = Tn; sval = svaln;
    }
    __syncthreads();
    // 3) OR kept rows (LDS buf[w&1]) into owned suppressed words > w
    unsigned long long kw = kwsh;
    if (tid < NWIN && tid > w) {
      unsigned long long acc = sup[tid];
      unsigned long long kc = kw;
      const unsigned long long* bw = &buf[w & 1][0];
      while (kc) {
        int ri = __ffsll((long long)kc) - 1;
        kc &= kc - 1;
        acc |= bw[(size_t)ri * NWORDS + tid];
      }
      sup[tid] = acc;
    }
    // 4) spill prefetched rows into the other buffer
    if (pf) {
      uint4* dst4 = (uint4*)&buf[(w + 1) & 1][0];
#pragma unroll
      for (int s = 0; s < 10; s++) {
        int c = tid + 256 * s;
        if (c < WCH) dst4[c] = r[s];
      }
    }
    __syncthreads();
  }
}

// ---------------- final outputs ----------------
__global__ void k_out(const float* __restrict__ ss, const uint32_t* __restrict__ sl,
                      const float* __restrict__ sb, const unsigned long long* __restrict__ keepw,
                      float* __restrict__ out) {
  int r = blockIdx.x * blockDim.x + threadIdx.x;
  if (r >= BN * KTOT) return;
  int b = r / KTOT;
  int e = r - b * KTOT;
  unsigned int kp = (unsigned int)((keepw[b * NWIN + (e >> 6)] >> (e & 63)) & 1ull);
  out[(size_t)r * 5 + 0] = sb[(size_t)r * 4 + 0];
  out[(size_t)r * 5 + 1] = sb[(size_t)r * 4 + 1];
  out[(size_t)r * 5 + 2] = sb[(size_t)r * 4 + 2];
  out[(size_t)r * 5 + 3] = sb[(size_t)r * 4 + 3];
  out[(size_t)r * 5 + 4] = ss[r];
  out[(size_t)BN * KTOT * 5 + r] = (float)sl[r];
  out[(size_t)BN * KTOT * 6 + r] = kp ? 1.0f : 0.0f;
}

extern "C" void kernel_launch(void* const* d_in, const int* in_sizes, int n_in,
                              void* d_out, int out_size, void* d_ws, size_t ws_size,
                              hipStream_t stream) {
  InPtrs ip;
  for (int l = 0; l < 5; l++) {
    ip.cls[l]  = (const float*)d_in[3 * l + 0];
    ip.bbox[l] = (const float*)d_in[3 * l + 1];
    ip.ctr[l]  = (const float*)d_in[3 * l + 2];
  }

  size_t off = 0;
  auto alloc = [&](size_t n) {
    char* p = (char*)d_ws + off;
    off = (off + n + 255) & ~(size_t)255;
    return p;
  };
  // mask rows padded to KTOT+64 per image so last-window speculative reads
  // stay inside the buffer.
  const size_t SU_BYTES   = (size_t)BN * TOT * 4;                  // 2.73 MB
  const size_t HIST_BYTES = 20ull * 65536 * 4;                     // 5.24 MB
  const size_t MASK_BYTES = (size_t)BN * (KTOT + 64) * NWORDS * 8; // 11.3 MB
  size_t region0 = ((SU_BYTES + 255) & ~(size_t)255) + HIST_BYTES;
  if (MASK_BYTES > region0) region0 = MASK_BYTES;
  char* r0p = (char*)alloc(region0);
  uint32_t* su   = (uint32_t*)r0p;
  uint32_t* hist = (uint32_t*)(r0p + ((SU_BYTES + 255) & ~(size_t)255));
  unsigned long long* mask = (unsigned long long*)r0p;

  uint32_t* mpfx   = (uint32_t*)alloc(20 * 4);
  uint32_t* mk     = (uint32_t*)alloc(20 * 4);
  uint32_t* selcnt = (uint32_t*)alloc(20 * 4);
  uint32_t* tiecnt = (uint32_t*)alloc(20 * 4);
  uint32_t* maxcb  = (uint32_t*)alloc(BN * 4);
  uint32_t* selu   = (uint32_t*)alloc(20ull * 1024 * 4);
  uint32_t* seli   = (uint32_t*)alloc(20ull * 1024 * 4);
  uint32_t* tiei   = (uint32_t*)alloc(20ull * TIE_CAP * 4);
  float*    ccs    = (float*)   alloc((size_t)BN * KTOT * 4);
  uint32_t* ccl    = (uint32_t*)alloc((size_t)BN * KTOT * 4);
  uint32_t* ccv    = (uint32_t*)alloc((size_t)BN * KTOT * 4);
  float*    ccb    = (float*)   alloc((size_t)BN * KTOT * 16);
  float*    ss     = (float*)   alloc((size_t)BN * KTOT * 4);
  uint32_t* sl     = (uint32_t*)alloc((size_t)BN * KTOT * 4);
  uint32_t* sv     = (uint32_t*)alloc((size_t)BN * KTOT * 4);
  float*    sb     = (float*)   alloc((size_t)BN * KTOT * 16);
  float*    ob     = (float*)   alloc((size_t)BN * KTOT * 16);
  unsigned long long* tdiag = (unsigned long long*)alloc((size_t)BN * NWIN * 64 * 8); // 148 KB
  unsigned long long* vbits = (unsigned long long*)alloc((size_t)BN * NWIN * 8);
  unsigned long long* keepw = (unsigned long long*)alloc((size_t)BN * NWIN * 8);
  (void)ws_size; (void)in_sizes; (void)n_in; (void)out_size;

  k_init<<<1, 64, 0, stream>>>(mk, mpfx, selcnt, tiecnt, maxcb);

  dim3 gscan((TOT + 255) / 256, BN);
  k_score<<<gscan, 256, 0, stream>>>(ip, su);
  for (int pass = 0; pass < 2; pass++) {
    hipMemsetAsync(hist, 0, HIST_BYTES, stream);
    k_histp<<<gscan, 256, 0, stream>>>(su, mpfx, hist, pass);
    k_findp<<<20, 1024, 0, stream>>>(hist, mpfx, mk, pass);
  }
  k_compact<<<gscan, 256, 0, stream>>>(su, mpfx, selcnt, tiecnt, selu, seli, tiei);
  k_ties<<<20, 256, 0, stream>>>(mpfx, mk, tiecnt, tiei, selu, seli);
  k_emit<<<dim3(20, 4), 256, 0, stream>>>(ip, selu, seli, ccs, ccl, ccv, ccb);
  k_sortimg<<<dim3(19, BN), 256, 0, stream>>>(ccs, ccl, ccv, ccb, ss, sl, sv, sb, maxcb);
  k_bits<<<dim3(NWIN, BN), 64, 0, stream>>>(sv, vbits);
  k_offset<<<(BN * KTOT + 255) / 256, 256, 0, stream>>>(sb, sl, maxcb, ob);
  k_mask<<<dim3(19, 5, BN), 256, 0, stream>>>(ob, mask, tdiag);
  k_nms<<<BN, 256, 0, stream>>>(mask, tdiag, vbits, keepw);
  k_out<<<(BN * KTOT + 255) / 256, 256, 0, stream>>>(ss, sl, sb, keepw, (float*)d_out);
}

// Round 11
// 1126.137 us; speedup vs baseline: 2.9956x; 1.1125x over previous
//
#include <hip/hip_runtime.h>
#include <stdint.h>

// FCOS bbox post-processing, B=4 images — bit-exact np/XLA-f32 replication
// (R7 semantics). R11: scatter-atomic k_nms.
//  - k_nms: window rows loaded to REGISTERS (predicated, words>w only);
//    scan overlaps the load latency; OR phase = per-thread scatter atomicOr
//    of nonzero held words into the LDS suppressed mask (sparse -> cheap).
//    tdiag/vbits LDS-staged once. No 37.9KB/window spill, no serial LDS
//    read chains.
//  - everything else identical to R10 (bit-exact chains).

#define BN 4
#define NC 80
#define TOT 170720       // 128000+32000+8000+2000+720
#define KTOT 4720        // 1000*4+720
#define NWORDS 74        // ceil(4720/64)
#define NWIN 74
#define TIE_CAP 4096
#define IMGSZ 320.0f
#define WCH 2368         // uint4 chunks per 64-row window (64*74*8/16)

struct InPtrs {
  const float* cls[5];
  const float* bbox[5];
  const float* ctr[5];
};

__device__ __forceinline__ uint32_t f2s(float f) {
  uint32_t x = __float_as_uint(f);
  return (x & 0x80000000u) ? ~x : (x | 0x80000000u);
}
__device__ __forceinline__ float s2f(uint32_t s) {
  uint32_t x = (s & 0x80000000u) ? (s & 0x7fffffffu) : ~s;
  return __uint_as_float(x);
}
// np/XLA logistic: 1/(1+exp(-x)) with per-op f32 rounding.
__device__ __forceinline__ float sigmoid32(float v) {
  float e = (float)exp(-(double)v);          // CR f32 exp(-v)
  return __fdiv_rn(1.0f, __fadd_rn(1.0f, e));
}
__device__ __forceinline__ void lvl_of(int e, int& l, int& le) {
  if (e < 128000)      { l = 0; le = e; }
  else if (e < 160000) { l = 1; le = e - 128000; }
  else if (e < 168000) { l = 2; le = e - 160000; }
  else if (e < 170000) { l = 3; le = e - 168000; }
  else                 { l = 4; le = e - 170000; }
}
__device__ __forceinline__ int kl_of(int l) {
  constexpr int KL[5] = {1000, 1000, 1000, 1000, 720};
  return KL[l];
}
__device__ __forceinline__ float clip32(float v) {
  return fminf(fmaxf(v, 0.0f), IMGSZ);
}
// IoU > 0.5 predicate, exact np f32 op chain (identical to R7-R10).
__device__ __forceinline__ int iou_gt(float bx1, float by1, float bx2, float by2,
                                      float bai, float4 o) {
  float ta_ = __fmul_rn(__fsub_rn(o.z, o.x), __fsub_rn(o.w, o.y));
  float ltx = fmaxf(bx1, o.x), lty = fmaxf(by1, o.y);
  float rbx = fminf(bx2, o.z), rby = fminf(by2, o.w);
  float wd = fmaxf(__fsub_rn(rbx, ltx), 0.0f);
  float hg = fmaxf(__fsub_rn(rby, lty), 0.0f);
  float inter = __fmul_rn(wd, hg);
  float asum = __fadd_rn(bai, ta_);
  float uni  = __fsub_rn(asum, inter);
  float iou  = (uni > 0.0f) ? __fdiv_rn(inter, uni) : 0.0f;
  return (iou > 0.5f) ? 1 : 0;
}

// ---------------- init state ----------------
__global__ void k_init(uint32_t* __restrict__ mk, uint32_t* __restrict__ mpfx,
                       uint32_t* __restrict__ selcnt, uint32_t* __restrict__ tiecnt,
                       uint32_t* __restrict__ maxcb) {
  int t = threadIdx.x;
  if (t < 20) {
    mk[t] = (uint32_t)kl_of(t % 5);
    mpfx[t] = 0u;
    selcnt[t] = 0u;
    tiecnt[t] = 0u;
  }
  if (t < BN) maxcb[t] = 0u;
}

// ---------------- scores -> sortable u32 keys ----------------
__global__ void k_score(InPtrs in, uint32_t* __restrict__ su) {
  int b = blockIdx.y;
  int e = blockIdx.x * blockDim.x + threadIdx.x;
  if (e >= TOT) return;
  int l, le; lvl_of(e, l, le);
  constexpr int HWc[5] = {1600, 400, 100, 25, 9};
  int hw = HWc[l];
  int c = le % NC, p = le / NC;
  float v = in.cls[l][((size_t)b * NC + c) * hw + p];
  float s = sigmoid32(v);
  float m = (s > 0.025f) ? s : -1.0f;
  su[(size_t)b * TOT + e] = f2s(m);
}

// ---------------- radix pass (16-bit digits, 2 passes) ----------------
__global__ void k_histp(const uint32_t* __restrict__ su, const uint32_t* __restrict__ mpfx,
                        uint32_t* __restrict__ hist, int pass) {
  int b = blockIdx.y;
  int e = blockIdx.x * blockDim.x + threadIdx.x;
  if (e >= TOT) return;
  int l, le; lvl_of(e, l, le);
  int bl = b * 5 + l;
  uint32_t key = su[(size_t)b * TOT + e];
  bool match = (pass == 0) ? true : ((key >> 16) == (mpfx[bl] >> 16));
  if (match) {
    uint32_t digit = (pass == 0) ? (key >> 16) : (key & 0xFFFFu);
    bool neg = (key == 0x407FFFFFu) && ((e & ~63) != 169984);
    if (neg) {
      unsigned long long mb2 = __ballot(1);
      int lead = __ffsll((long long)mb2) - 1;
      if ((threadIdx.x & 63) == lead)
        atomicAdd(&hist[(size_t)bl * 65536u + digit], (uint32_t)__popcll(mb2));
    } else {
      atomicAdd(&hist[(size_t)bl * 65536u + digit], 1u);
    }
  }
}

__global__ void k_findp(const uint32_t* __restrict__ hist, uint32_t* __restrict__ mpfx,
                        uint32_t* __restrict__ mk, int pass) {
  int bl = blockIdx.x;
  uint32_t k = mk[bl];
  uint32_t pfx = mpfx[bl];
  const uint32_t* h = hist + (size_t)bl * 65536;
  __shared__ uint32_t sh[1024];
  int tid = threadIdx.x;
  int base = tid * 64;
  uint32_t s = 0;
  for (int i = 0; i < 64; i++) s += h[base + i];
  sh[tid] = s;
  __syncthreads();
  uint32_t above = 0;
  for (int t = tid + 1; t < 1024; t++) above += sh[t];
  if (above < k && above + s >= k) {
    uint32_t cum = above;
    for (int bin = base + 63; bin >= base; bin--) {
      uint32_t c = h[bin];
      if (cum < k && cum + c >= k) {
        if (pass == 0) mpfx[bl] = (uint32_t)bin << 16;
        else           mpfx[bl] = pfx | (uint32_t)bin;
        mk[bl] = k - cum;
        break;
      }
      cum += c;
    }
  }
}

// ---------------- compact selected ----------------
__global__ void k_compact(const uint32_t* __restrict__ su, const uint32_t* __restrict__ mpfx,
                          uint32_t* __restrict__ selcnt, uint32_t* __restrict__ tiecnt,
                          uint32_t* __restrict__ selu, uint32_t* __restrict__ seli,
                          uint32_t* __restrict__ tiei) {
  int b = blockIdx.y;
  int e = blockIdx.x * blockDim.x + threadIdx.x;
  if (e >= TOT) return;
  int l, le; lvl_of(e, l, le);
  int bl = b * 5 + l;
  uint32_t u = su[(size_t)b * TOT + e];
  uint32_t C = mpfx[bl];
  if (u > C) {
    uint32_t pos = atomicAdd(&selcnt[bl], 1u);
    selu[(size_t)bl * 1024 + pos] = u;
    seli[(size_t)bl * 1024 + pos] = (uint32_t)le;
  } else if (u == C) {
    uint32_t pos = atomicAdd(&tiecnt[bl], 1u);
    if (pos < TIE_CAP) tiei[(size_t)bl * TIE_CAP + pos] = (uint32_t)le;
  }
}

// Boundary ties: stable top_k -> smallest indices first.
__global__ void k_ties(const uint32_t* __restrict__ mpfx, const uint32_t* __restrict__ mk,
                       const uint32_t* __restrict__ tiecnt, const uint32_t* __restrict__ tiei,
                       uint32_t* __restrict__ selu, uint32_t* __restrict__ seli) {
  int bl = blockIdx.x;
  int l = bl % 5;
  uint32_t C = mpfx[bl];
  uint32_t T = mk[bl];
  uint32_t G = (uint32_t)kl_of(l) - T;
  uint32_t Tc = tiecnt[bl];
  if (Tc > TIE_CAP) Tc = TIE_CAP;
  __shared__ uint32_t sh[TIE_CAP];
  for (uint32_t t = threadIdx.x; t < Tc; t += blockDim.x) sh[t] = tiei[(size_t)bl * TIE_CAP + t];
  __syncthreads();
  for (uint32_t t = threadIdx.x; t < Tc; t += blockDim.x) {
    uint32_t my = sh[t];
    uint32_t rank = 0;
    for (uint32_t q = 0; q < Tc; q++) rank += (sh[q] < my) ? 1u : 0u;
    if (rank < T) {
      selu[(size_t)bl * 1024 + G + rank] = C;
      seli[(size_t)bl * 1024 + G + rank] = my;
    }
  }
}

// ---------------- exact rank within level + emit (packed u64 keys) --------------
__global__ void k_emit(InPtrs in, const uint32_t* __restrict__ selu, const uint32_t* __restrict__ seli,
                       float* __restrict__ ccs, uint32_t* __restrict__ ccl,
                       uint32_t* __restrict__ ccv, float* __restrict__ ccb) {
  int bl = blockIdx.x;
  int chunk = blockIdx.y;
  int b = bl / 5, l = bl % 5;
  int k = kl_of(l);
  __shared__ uint64_t z[1024];   // 8 KB
  int tid = threadIdx.x;
  for (int t = tid; t < 1024; t += 256) {
    if (t < k) {
      uint32_t u = selu[(size_t)bl * 1024 + t];
      uint32_t idx = seli[(size_t)bl * 1024 + t];
      z[t] = (((uint64_t)u) << 32) | (uint32_t)(~idx);
    } else z[t] = 0ull;
  }
  __syncthreads();
  int tg = chunk * 256 + tid;
  if (tg >= k) return;
  uint64_t zi = z[tg];
  uint32_t u = (uint32_t)(zi >> 32);
  uint32_t idx = ~(uint32_t)zi;
  int rank = 0;
  const uint4* z4 = (const uint4*)z;
  for (int j4 = 0; j4 < 512; j4++) {
    uint4 q = z4[j4];
    uint64_t za = (((uint64_t)q.y) << 32) | q.x;
    uint64_t zb = (((uint64_t)q.w) << 32) | q.z;
    rank += (za > zi) ? 1 : 0;
    rank += (zb > zi) ? 1 : 0;
  }
  constexpr int Wc[5]  = {40, 20, 10, 5, 3};
  constexpr int HWc[5] = {1600, 400, 100, 25, 9};
  constexpr float Sc[5] = {8.f, 16.f, 32.f, 64.f, 128.f};
  constexpr int COFF[5] = {0, 1000, 2000, 3000, 4000};
  int w = Wc[l], hw = HWc[l];
  float ms = s2f(u);
  int valid = (ms > 0.025f) ? 1 : 0;
  int p = (int)idx / NC, c = (int)idx % NC;
  int x = p % w, y = p / w;
  float sf = sigmoid32(in.ctr[l][(size_t)b * hw + p]);
  float score = valid ? __fmul_rn(ms, sf) : -1.0f;
  float px = __fmul_rn(__fadd_rn((float)x, 0.5f), Sc[l]);
  float py = __fmul_rn(__fadd_rn((float)y, 0.5f), Sc[l]);
  size_t bb = (size_t)b * 4 * hw;
  float d0 = in.bbox[l][bb + 0 * hw + p];
  float d1 = in.bbox[l][bb + 1 * hw + p];
  float d2 = in.bbox[l][bb + 2 * hw + p];
  float d3 = in.bbox[l][bb + 3 * hw + p];
  float x1 = clip32(__fsub_rn(px, d0)), y1 = clip32(__fsub_rn(py, d1));
  float x2 = clip32(__fadd_rn(px, d2)), y2 = clip32(__fadd_rn(py, d3));
  int o = b * KTOT + COFF[l] + rank;
  ccs[o] = score;
  ccl[o] = (uint32_t)c;
  ccv[o] = (uint32_t)valid;
  ccb[(size_t)o * 4 + 0] = x1; ccb[(size_t)o * 4 + 1] = y1;
  ccb[(size_t)o * 4 + 2] = x2; ccb[(size_t)o * 4 + 3] = y2;
}

// ---------------- per-image stable descending sort (rank method) ----------------
__global__ void k_sortimg(const float* __restrict__ ccs, const uint32_t* __restrict__ ccl,
                          const uint32_t* __restrict__ ccv, const float* __restrict__ ccb,
                          float* __restrict__ ss, uint32_t* __restrict__ sl,
                          uint32_t* __restrict__ sv, float* __restrict__ sb,
                          uint32_t* __restrict__ maxcb) {
  int b = blockIdx.y;
  __shared__ uint32_t key[KTOT];   // 18.9 KB
  int tid = threadIdx.x;
  for (int e = tid; e < KTOT; e += 256) key[e] = f2s(ccs[(size_t)b * KTOT + e]);
  __syncthreads();
  int e = blockIdx.x * 256 + tid;
  if (e >= KTOT) return;
  uint32_t ke = key[e];
  int rank = 0;
  const uint4* k4 = (const uint4*)key;
  for (int j4 = 0; j4 < KTOT / 4; j4++) {
    uint4 kk = k4[j4];
    int j = j4 * 4;
    rank += ((kk.x > ke) || (kk.x == ke && (j + 0) < e)) ? 1 : 0;
    rank += ((kk.y > ke) || (kk.y == ke && (j + 1) < e)) ? 1 : 0;
    rank += ((kk.z > ke) || (kk.z == ke && (j + 2) < e)) ? 1 : 0;
    rank += ((kk.w > ke) || (kk.w == ke && (j + 3) < e)) ? 1 : 0;
  }
  int sidx = b * KTOT + e;
  int d = b * KTOT + rank;
  ss[d] = ccs[sidx];
  sl[d] = ccl[sidx];
  sv[d] = ccv[sidx];
  float b0 = ccb[(size_t)sidx * 4 + 0], b1 = ccb[(size_t)sidx * 4 + 1];
  float b2 = ccb[(size_t)sidx * 4 + 2], b3 = ccb[(size_t)sidx * 4 + 3];
  sb[(size_t)d * 4 + 0] = b0; sb[(size_t)d * 4 + 1] = b1;
  sb[(size_t)d * 4 + 2] = b2; sb[(size_t)d * 4 + 3] = b3;
  float mx = fmaxf(fmaxf(b0, b1), fmaxf(b2, b3));
  atomicMax(&maxcb[b], __float_as_uint(mx));
}

// ---------------- valid bits -> bitmask words ----------------
__global__ void k_bits(const uint32_t* __restrict__ sv, unsigned long long* __restrict__ vbits) {
  int w = blockIdx.x, b = blockIdx.y, lane = threadIdx.x;
  int e = w * 64 + lane;
  int pred = (e < KTOT) ? (sv[(size_t)b * KTOT + e] != 0u) : 0;
  unsigned long long m = __ballot(pred);
  if (lane == 0) vbits[b * NWIN + w] = m;
}

// ---------------- per-class offset boxes (f32) ----------------
__global__ void k_offset(const float* __restrict__ sb, const uint32_t* __restrict__ sl,
                         const uint32_t* __restrict__ maxcb, float* __restrict__ ob) {
  int r = blockIdx.x * blockDim.x + threadIdx.x;
  if (r >= BN * KTOT) return;
  int b = r / KTOT;
  float scale = __fadd_rn(__uint_as_float(maxcb[b]), 1.0f);
  float offv = __fmul_rn((float)sl[r], scale);
  float x1 = __fadd_rn(sb[(size_t)r * 4 + 0], offv);
  float y1 = __fadd_rn(sb[(size_t)r * 4 + 1], offv);
  float x2 = __fadd_rn(sb[(size_t)r * 4 + 2], offv);
  float y2 = __fadd_rn(sb[(size_t)r * 4 + 3], offv);
  ob[(size_t)r * 4 + 0] = x1; ob[(size_t)r * 4 + 1] = y1;
  ob[(size_t)r * 4 + 2] = x2; ob[(size_t)r * 4 + 3] = y2;
}

// ---------------- IoU bitmask, 2D-tiled (R9) ----------------
__global__ void k_mask(const float* __restrict__ ob, unsigned long long* __restrict__ mask,
                       unsigned long long* __restrict__ tdiag) {
  int b = blockIdx.z;
  int jt = blockIdx.y;
  int ib = blockIdx.x;
  int jbase = jt * 1024;
  int cnt = min(1024, KTOT - jbase);
  bool diagBlock = (jt == (ib >> 2));
  if (!diagBlock && (jbase + cnt - 1 <= ib * 256)) return;
  __shared__ float4 tb[1024];   // 16 KB
  int tid = threadIdx.x;
  for (int j = tid; j < cnt; j += 256)
    tb[j] = ((const float4*)ob)[(size_t)b * KTOT + jbase + j];
  __syncthreads();
  int i = ib * 256 + tid;
  bool act = (i < KTOT);
  float bx1 = 0, by1 = 0, bx2 = 0, by2 = 0, bai = 0;
  if (act) {
    float4 v = ((const float4*)ob)[(size_t)b * KTOT + i];
    bx1 = v.x; by1 = v.y; bx2 = v.z; by2 = v.w;
    bai = __fmul_rn(__fsub_rn(bx2, bx1), __fsub_rn(by2, by1));
  }
  int myw = i >> 6;
  unsigned long long dw = 0ull;
  if (act) {
    unsigned long long* mrow = mask + ((size_t)b * (KTOT + 64) + i) * NWORDS;
    int nw = (cnt + 63) >> 6;
    for (int w = 0; w < nw; w++) {
      int gw = jt * 16 + w;
      if (gw < myw) continue;
      unsigned long long bits = 0ull;
      int j0 = w * 64;
      int jn = min(64, cnt - j0);
      if (gw == myw) {
        for (int jj = 0; jj < jn; jj++) {
          if (jbase + j0 + jj > i)
            bits |= ((unsigned long long)iou_gt(bx1, by1, bx2, by2, bai, tb[j0 + jj])) << jj;
        }
        dw = bits;
      } else {
        for (int jj = 0; jj < jn; jj++)
          bits |= ((unsigned long long)iou_gt(bx1, by1, bx2, by2, bai, tb[j0 + jj])) << jj;
        mrow[gw] = bits;
      }
    }
  }
  if (diagBlock) {
    int lane = tid & 63;
    unsigned long long col = 0ull;
#pragma unroll
    for (int j = 0; j < 64; j++) {
      unsigned long long bal = __ballot((int)((dw >> j) & 1ull));
      if (lane == j) col = bal;
    }
    if (myw < NWIN) tdiag[((size_t)b * NWIN + (size_t)myw) * 64 + lane] = col;
  }
}

// ---------------- scatter-atomic blocked greedy NMS, 256 thr/image --------------
// LDS: tdiag copy (37888 B) + vbits (592 B) + sup mask (592 B) + kw.
// Per window w: (1) all threads issue predicated register loads of window-w
// rows (words > w only); (2) wave-0 readlane diagonal scan (sup[w] consumed
// here, before any window-w contribution); barrier (drains the loads exactly
// when needed); (3) each thread scatter-ORs its held nonzero words of kept
// rows into sup via 32-bit LDS atomics (sparse -> few real atomics); barrier.
__global__ void k_nms(const unsigned long long* __restrict__ mask,
                      const unsigned long long* __restrict__ tdiag,
                      const unsigned long long* __restrict__ vbits,
                      unsigned long long* __restrict__ keepw) {
  int b = blockIdx.x;
  int tid = threadIdx.x;
  int lane = tid & 63;
  int wv = tid >> 6;
  const unsigned long long* mb = mask + (size_t)b * (KTOT + 64) * NWORDS;
  __shared__ unsigned long long tdl[NWIN * 64];   // 37888 B
  __shared__ unsigned long long svl[NWIN];
  __shared__ unsigned long long sup[NWIN];
  __shared__ unsigned long long kwsh;
  {
    const uint4* src = (const uint4*)(tdiag + (size_t)b * NWIN * 64);
    uint4* dst = (uint4*)tdl;
#pragma unroll
    for (int s = 0; s < 10; s++) {
      int c = tid + 256 * s;
      if (c < WCH) dst[c] = src[c];   // NWIN*64 u64 == WCH uint4
    }
  }
  if (tid < NWIN) { svl[tid] = vbits[b * NWIN + tid]; sup[tid] = 0ull; }
  __syncthreads();
  unsigned int* sup32 = (unsigned int*)sup;
  for (int w = 0; w < NWIN; w++) {
    // 1) register loads of this window's rows (useful words only)
    uint4 q[10];
    const uint4* src4 = (const uint4*)(mb + (size_t)w * 64 * NWORDS);
#pragma unroll
    for (int s = 0; s < 10; s++) {
      int c = tid + 256 * s;
      if (c < WCH && (2 * (c % 37) + 1 > w)) q[s] = src4[c];
    }
    // 2) wave-0 diagonal scan
    if (wv == 0) {
      unsigned long long T = tdl[w * 64 + lane];
      unsigned long long sval = svl[w];
      unsigned long long s_in = sup[w];
      unsigned int supb = (unsigned int)((s_in >> lane) & 1ull);
      unsigned int Tlo = (unsigned int)T, Thi = (unsigned int)(T >> 32);
      unsigned int svlo = (unsigned int)sval, svhi = (unsigned int)(sval >> 32);
      unsigned long long kw = 0ull;
#pragma unroll
      for (int i = 0; i < 64; i++) {
        unsigned int si = (unsigned int)__builtin_amdgcn_readlane((int)supb, i);
        unsigned int vi = ((i < 32 ? svlo : svhi) >> (i & 31)) & 1u;
        unsigned int kp = vi & (si ^ 1u) & 1u;
        kw |= ((unsigned long long)kp) << i;
        unsigned int tbv = ((i < 32 ? Tlo : Thi) >> (i & 31)) & 1u;
        supb |= tbv & kp;
      }
      if (lane == 0) { keepw[b * NWIN + w] = kw; kwsh = kw; }
    }
    __syncthreads();   // kwsh visible; q[] loads drained here (vmcnt 0)
    // 3) scatter-OR held nonzero words of kept rows into sup (words > w)
    unsigned long long kw = kwsh;
#pragma unroll
    for (int s = 0; s < 10; s++) {
      int c = tid + 256 * s;
      if (c >= WCH) continue;
      int wp = c % 37;
      if (2 * wp + 1 <= w) continue;
      int r = c / 37;
      if (!((kw >> r) & 1ull)) continue;
      int wlo = 2 * wp, whi = 2 * wp + 1;   // u64 word indices of this chunk
      if (wlo > w) {
        if (q[s].x) atomicOr(&sup32[2 * wlo + 0], q[s].x);
        if (q[s].y) atomicOr(&sup32[2 * wlo + 1], q[s].y);
      }
      if (whi > w) {
        if (q[s].z) atomicOr(&sup32[2 * whi + 0], q[s].z);
        if (q[s].w) atomicOr(&sup32[2 * whi + 1], q[s].w);
      }
    }
    __syncthreads();
  }
}

// ---------------- final outputs ----------------
__global__ void k_out(const float* __restrict__ ss, const uint32_t* __restrict__ sl,
                      const float* __restrict__ sb, const unsigned long long* __restrict__ keepw,
                      float* __restrict__ out) {
  int r = blockIdx.x * blockDim.x + threadIdx.x;
  if (r >= BN * KTOT) return;
  int b = r / KTOT;
  int e = r - b * KTOT;
  unsigned int kp = (unsigned int)((keepw[b * NWIN + (e >> 6)] >> (e & 63)) & 1ull);
  out[(size_t)r * 5 + 0] = sb[(size_t)r * 4 + 0];
  out[(size_t)r * 5 + 1] = sb[(size_t)r * 4 + 1];
  out[(size_t)r * 5 + 2] = sb[(size_t)r * 4 + 2];
  out[(size_t)r * 5 + 3] = sb[(size_t)r * 4 + 3];
  out[(size_t)r * 5 + 4] = ss[r];
  out[(size_t)BN * KTOT * 5 + r] = (float)sl[r];
  out[(size_t)BN * KTOT * 6 + r] = kp ? 1.0f : 0.0f;
}

extern "C" void kernel_launch(void* const* d_in, const int* in_sizes, int n_in,
                              void* d_out, int out_size, void* d_ws, size_t ws_size,
                              hipStream_t stream) {
  InPtrs ip;
  for (int l = 0; l < 5; l++) {
    ip.cls[l]  = (const float*)d_in[3 * l + 0];
    ip.bbox[l] = (const float*)d_in[3 * l + 1];
    ip.ctr[l]  = (const float*)d_in[3 * l + 2];
  }

  size_t off = 0;
  auto alloc = [&](size_t n) {
    char* p = (char*)d_ws + off;
    off = (off + n + 255) & ~(size_t)255;
    return p;
  };
  // mask rows padded to KTOT+64 per image (last-window speculative loads).
  const size_t SU_BYTES   = (size_t)BN * TOT * 4;                  // 2.73 MB
  const size_t HIST_BYTES = 20ull * 65536 * 4;                     // 5.24 MB
  const size_t MASK_BYTES = (size_t)BN * (KTOT + 64) * NWORDS * 8; // 11.3 MB
  size_t region0 = ((SU_BYTES + 255) & ~(size_t)255) + HIST_BYTES;
  if (MASK_BYTES > region0) region0 = MASK_BYTES;
  char* r0p = (char*)alloc(region0);
  uint32_t* su   = (uint32_t*)r0p;
  uint32_t* hist = (uint32_t*)(r0p + ((SU_BYTES + 255) & ~(size_t)255));
  unsigned long long* mask = (unsigned long long*)r0p;

  uint32_t* mpfx   = (uint32_t*)alloc(20 * 4);
  uint32_t* mk     = (uint32_t*)alloc(20 * 4);
  uint32_t* selcnt = (uint32_t*)alloc(20 * 4);
  uint32_t* tiecnt = (uint32_t*)alloc(20 * 4);
  uint32_t* maxcb  = (uint32_t*)alloc(BN * 4);
  uint32_t* selu   = (uint32_t*)alloc(20ull * 1024 * 4);
  uint32_t* seli   = (uint32_t*)alloc(20ull * 1024 * 4);
  uint32_t* tiei   = (uint32_t*)alloc(20ull * TIE_CAP * 4);
  float*    ccs    = (float*)   alloc((size_t)BN * KTOT * 4);
  uint32_t* ccl    = (uint32_t*)alloc((size_t)BN * KTOT * 4);
  uint32_t* ccv    = (uint32_t*)alloc((size_t)BN * KTOT * 4);
  float*    ccb    = (float*)   alloc((size_t)BN * KTOT * 16);
  float*    ss     = (float*)   alloc((size_t)BN * KTOT * 4);
  uint32_t* sl     = (uint32_t*)alloc((size_t)BN * KTOT * 4);
  uint32_t* sv     = (uint32_t*)alloc((size_t)BN * KTOT * 4);
  float*    sb     = (float*)   alloc((size_t)BN * KTOT * 16);
  float*    ob     = (float*)   alloc((size_t)BN * KTOT * 16);
  unsigned long long* tdiag = (unsigned long long*)alloc((size_t)BN * NWIN * 64 * 8); // 148 KB
  unsigned long long* vbits = (unsigned long long*)alloc((size_t)BN * NWIN * 8);
  unsigned long long* keepw = (unsigned long long*)alloc((size_t)BN * NWIN * 8);
  (void)ws_size; (void)in_sizes; (void)n_in; (void)out_size;

  k_init<<<1, 64, 0, stream>>>(mk, mpfx, selcnt, tiecnt, maxcb);

  dim3 gscan((TOT + 255) / 256, BN);
  k_score<<<gscan, 256, 0, stream>>>(ip, su);
  for (int pass = 0; pass < 2; pass++) {
    hipMemsetAsync(hist, 0, HIST_BYTES, stream);
    k_histp<<<gscan, 256, 0, stream>>>(su, mpfx, hist, pass);
    k_findp<<<20, 1024, 0, stream>>>(hist, mpfx, mk, pass);
  }
  k_compact<<<gscan, 256, 0, stream>>>(su, mpfx, selcnt, tiecnt, selu, seli, tiei);
  k_ties<<<20, 256, 0, stream>>>(mpfx, mk, tiecnt, tiei, selu, seli);
  k_emit<<<dim3(20, 4), 256, 0, stream>>>(ip, selu, seli, ccs, ccl, ccv, ccb);
  k_sortimg<<<dim3(19, BN), 256, 0, stream>>>(ccs, ccl, ccv, ccb, ss, sl, sv, sb, maxcb);
  k_bits<<<dim3(NWIN, BN), 64, 0, stream>>>(sv, vbits);
  k_offset<<<(BN * KTOT + 255) / 256, 256, 0, stream>>>(sb, sl, maxcb, ob);
  k_mask<<<dim3(19, 5, BN), 256, 0, stream>>>(ob, mask, tdiag);
  k_nms<<<BN, 256, 0, stream>>>(mask, tdiag, vbits, keepw);
  k_out<<<(BN * KTOT + 255) / 256, 256, 0, stream>>>(ss, sl, sb, keepw, (float*)d_out);
}

// Round 12
// 871.990 us; speedup vs baseline: 3.8687x; 1.2915x over previous
//
#include <hip/hip_runtime.h>
#include <stdint.h>

// FCOS bbox post-processing, B=4 images — bit-exact np/XLA-f32 replication
// (R7 semantics). R12: sparse-pair NMS.
//  - k_mask additionally emits compact suppression pairs ((i<<13)|j) for
//    strictly-upper words; dense mask retained for the (improbable) fallback.
//  - k_nms: pairs staged in LDS; window loop = wave-0 readlane scan +
//    pair-scatter LDS atomicOr. No global loads in the loop. Fallbacks:
//    global pair scan (<=128k pairs) and R11 dense loop (beyond).
//  - k_score folds radix pass-0 histogram; k_init eliminated.

#define BN 4
#define NC 80
#define TOT 170720       // 128000+32000+8000+2000+720
#define KTOT 4720        // 1000*4+720
#define NWORDS 74        // ceil(4720/64)
#define NWIN 74
#define TIE_CAP 4096
#define IMGSZ 320.0f
#define WCH 2368         // uint4 chunks per 64-row window (64*74*8/16)
#define PAIR_CAP 131072  // pairs per image (global)
#define LDSP 12288       // pairs staged in LDS

struct InPtrs {
  const float* cls[5];
  const float* bbox[5];
  const float* ctr[5];
};

__device__ __forceinline__ uint32_t f2s(float f) {
  uint32_t x = __float_as_uint(f);
  return (x & 0x80000000u) ? ~x : (x | 0x80000000u);
}
__device__ __forceinline__ float s2f(uint32_t s) {
  uint32_t x = (s & 0x80000000u) ? (s & 0x7fffffffu) : ~s;
  return __uint_as_float(x);
}
// np/XLA logistic: 1/(1+exp(-x)) with per-op f32 rounding.
__device__ __forceinline__ float sigmoid32(float v) {
  float e = (float)exp(-(double)v);          // CR f32 exp(-v)
  return __fdiv_rn(1.0f, __fadd_rn(1.0f, e));
}
__device__ __forceinline__ void lvl_of(int e, int& l, int& le) {
  if (e < 128000)      { l = 0; le = e; }
  else if (e < 160000) { l = 1; le = e - 128000; }
  else if (e < 168000) { l = 2; le = e - 160000; }
  else if (e < 170000) { l = 3; le = e - 168000; }
  else                 { l = 4; le = e - 170000; }
}
__device__ __forceinline__ int kl_of(int l) {
  constexpr int KL[5] = {1000, 1000, 1000, 1000, 720};
  return KL[l];
}
__device__ __forceinline__ float clip32(float v) {
  return fminf(fmaxf(v, 0.0f), IMGSZ);
}
// IoU > 0.5 predicate, exact np f32 op chain (identical to R7-R11).
__device__ __forceinline__ int iou_gt(float bx1, float by1, float bx2, float by2,
                                      float bai, float4 o) {
  float ta_ = __fmul_rn(__fsub_rn(o.z, o.x), __fsub_rn(o.w, o.y));
  float ltx = fmaxf(bx1, o.x), lty = fmaxf(by1, o.y);
  float rbx = fminf(bx2, o.z), rby = fminf(by2, o.w);
  float wd = fmaxf(__fsub_rn(rbx, ltx), 0.0f);
  float hg = fmaxf(__fsub_rn(rby, lty), 0.0f);
  float inter = __fmul_rn(wd, hg);
  float asum = __fadd_rn(bai, ta_);
  float uni  = __fsub_rn(asum, inter);
  float iou  = (uni > 0.0f) ? __fdiv_rn(inter, uni) : 0.0f;
  return (iou > 0.5f) ? 1 : 0;
}

// ---------------- scores -> sortable u32 keys + pass-0 histogram ----------------
__global__ void k_score(InPtrs in, uint32_t* __restrict__ su, uint32_t* __restrict__ hist) {
  int b = blockIdx.y;
  int e = blockIdx.x * blockDim.x + threadIdx.x;
  if (e >= TOT) return;
  int l, le; lvl_of(e, l, le);
  constexpr int HWc[5] = {1600, 400, 100, 25, 9};
  int hw = HWc[l];
  int c = le % NC, p = le / NC;
  float v = in.cls[l][((size_t)b * NC + c) * hw + p];
  float s = sigmoid32(v);
  float m = (s > 0.025f) ? s : -1.0f;
  uint32_t u = f2s(m);
  su[(size_t)b * TOT + e] = u;
  atomicAdd(&hist[(size_t)(b * 5 + l) * 65536u + (u >> 16)], 1u);
}

// ---------------- radix pass 1: low-16 histogram of matching keys ---------------
__global__ void k_hist1(const uint32_t* __restrict__ su, const uint32_t* __restrict__ mpfx,
                        uint32_t* __restrict__ hist) {
  int b = blockIdx.y;
  int e = blockIdx.x * blockDim.x + threadIdx.x;
  if (e >= TOT) return;
  int l, le; lvl_of(e, l, le);
  int bl = b * 5 + l;
  uint32_t key = su[(size_t)b * TOT + e];
  if ((key >> 16) == (mpfx[bl] >> 16))
    atomicAdd(&hist[(size_t)bl * 65536u + (key & 0xFFFFu)], 1u);
}

__global__ void k_findp(const uint32_t* __restrict__ hist, uint32_t* __restrict__ mpfx,
                        uint32_t* __restrict__ mk, int pass) {
  int bl = blockIdx.x;
  uint32_t k = (pass == 0) ? (uint32_t)kl_of(bl % 5) : mk[bl];
  uint32_t pfx = (pass == 0) ? 0u : mpfx[bl];
  const uint32_t* h = hist + (size_t)bl * 65536;
  __shared__ uint32_t sh[1024];
  int tid = threadIdx.x;
  int base = tid * 64;
  uint32_t s = 0;
  for (int i = 0; i < 64; i++) s += h[base + i];
  sh[tid] = s;
  __syncthreads();
  uint32_t above = 0;
  for (int t = tid + 1; t < 1024; t++) above += sh[t];
  if (above < k && above + s >= k) {
    uint32_t cum = above;
    for (int bin = base + 63; bin >= base; bin--) {
      uint32_t c = h[bin];
      if (cum < k && cum + c >= k) {
        if (pass == 0) mpfx[bl] = (uint32_t)bin << 16;
        else           mpfx[bl] = pfx | (uint32_t)bin;
        mk[bl] = k - cum;
        break;
      }
      cum += c;
    }
  }
}

// ---------------- compact selected ----------------
__global__ void k_compact(const uint32_t* __restrict__ su, const uint32_t* __restrict__ mpfx,
                          uint32_t* __restrict__ selcnt, uint32_t* __restrict__ tiecnt,
                          uint32_t* __restrict__ selu, uint32_t* __restrict__ seli,
                          uint32_t* __restrict__ tiei) {
  int b = blockIdx.y;
  int e = blockIdx.x * blockDim.x + threadIdx.x;
  if (e >= TOT) return;
  int l, le; lvl_of(e, l, le);
  int bl = b * 5 + l;
  uint32_t u = su[(size_t)b * TOT + e];
  uint32_t C = mpfx[bl];
  if (u > C) {
    uint32_t pos = atomicAdd(&selcnt[bl], 1u);
    selu[(size_t)bl * 1024 + pos] = u;
    seli[(size_t)bl * 1024 + pos] = (uint32_t)le;
  } else if (u == C) {
    uint32_t pos = atomicAdd(&tiecnt[bl], 1u);
    if (pos < TIE_CAP) tiei[(size_t)bl * TIE_CAP + pos] = (uint32_t)le;
  }
}

// Boundary ties: stable top_k -> smallest indices first.
__global__ void k_ties(const uint32_t* __restrict__ mpfx, const uint32_t* __restrict__ mk,
                       const uint32_t* __restrict__ tiecnt, const uint32_t* __restrict__ tiei,
                       uint32_t* __restrict__ selu, uint32_t* __restrict__ seli) {
  int bl = blockIdx.x;
  int l = bl % 5;
  uint32_t C = mpfx[bl];
  uint32_t T = mk[bl];
  uint32_t G = (uint32_t)kl_of(l) - T;
  uint32_t Tc = tiecnt[bl];
  if (Tc > TIE_CAP) Tc = TIE_CAP;
  __shared__ uint32_t sh[TIE_CAP];
  for (uint32_t t = threadIdx.x; t < Tc; t += blockDim.x) sh[t] = tiei[(size_t)bl * TIE_CAP + t];
  __syncthreads();
  for (uint32_t t = threadIdx.x; t < Tc; t += blockDim.x) {
    uint32_t my = sh[t];
    uint32_t rank = 0;
    for (uint32_t q = 0; q < Tc; q++) rank += (sh[q] < my) ? 1u : 0u;
    if (rank < T) {
      selu[(size_t)bl * 1024 + G + rank] = C;
      seli[(size_t)bl * 1024 + G + rank] = my;
    }
  }
}

// ---------------- exact rank within level + emit (packed u64 keys) --------------
__global__ void k_emit(InPtrs in, const uint32_t* __restrict__ selu, const uint32_t* __restrict__ seli,
                       float* __restrict__ ccs, uint32_t* __restrict__ ccl,
                       uint32_t* __restrict__ ccv, float* __restrict__ ccb) {
  int bl = blockIdx.x;
  int chunk = blockIdx.y;
  int b = bl / 5, l = bl % 5;
  int k = kl_of(l);
  __shared__ uint64_t z[1024];   // 8 KB
  int tid = threadIdx.x;
  for (int t = tid; t < 1024; t += 256) {
    if (t < k) {
      uint32_t u = selu[(size_t)bl * 1024 + t];
      uint32_t idx = seli[(size_t)bl * 1024 + t];
      z[t] = (((uint64_t)u) << 32) | (uint32_t)(~idx);
    } else z[t] = 0ull;
  }
  __syncthreads();
  int tg = chunk * 256 + tid;
  if (tg >= k) return;
  uint64_t zi = z[tg];
  uint32_t u = (uint32_t)(zi >> 32);
  uint32_t idx = ~(uint32_t)zi;
  int rank = 0;
  const uint4* z4 = (const uint4*)z;
  for (int j4 = 0; j4 < 512; j4++) {
    uint4 q = z4[j4];
    uint64_t za = (((uint64_t)q.y) << 32) | q.x;
    uint64_t zb = (((uint64_t)q.w) << 32) | q.z;
    rank += (za > zi) ? 1 : 0;
    rank += (zb > zi) ? 1 : 0;
  }
  constexpr int Wc[5]  = {40, 20, 10, 5, 3};
  constexpr int HWc[5] = {1600, 400, 100, 25, 9};
  constexpr float Sc[5] = {8.f, 16.f, 32.f, 64.f, 128.f};
  constexpr int COFF[5] = {0, 1000, 2000, 3000, 4000};
  int w = Wc[l], hw = HWc[l];
  float ms = s2f(u);
  int valid = (ms > 0.025f) ? 1 : 0;
  int p = (int)idx / NC, c = (int)idx % NC;
  int x = p % w, y = p / w;
  float sf = sigmoid32(in.ctr[l][(size_t)b * hw + p]);
  float score = valid ? __fmul_rn(ms, sf) : -1.0f;
  float px = __fmul_rn(__fadd_rn((float)x, 0.5f), Sc[l]);
  float py = __fmul_rn(__fadd_rn((float)y, 0.5f), Sc[l]);
  size_t bb = (size_t)b * 4 * hw;
  float d0 = in.bbox[l][bb + 0 * hw + p];
  float d1 = in.bbox[l][bb + 1 * hw + p];
  float d2 = in.bbox[l][bb + 2 * hw + p];
  float d3 = in.bbox[l][bb + 3 * hw + p];
  float x1 = clip32(__fsub_rn(px, d0)), y1 = clip32(__fsub_rn(py, d1));
  float x2 = clip32(__fadd_rn(px, d2)), y2 = clip32(__fadd_rn(py, d3));
  int o = b * KTOT + COFF[l] + rank;
  ccs[o] = score;
  ccl[o] = (uint32_t)c;
  ccv[o] = (uint32_t)valid;
  ccb[(size_t)o * 4 + 0] = x1; ccb[(size_t)o * 4 + 1] = y1;
  ccb[(size_t)o * 4 + 2] = x2; ccb[(size_t)o * 4 + 3] = y2;
}

// ---------------- per-image stable descending sort (rank method) ----------------
__global__ void k_sortimg(const float* __restrict__ ccs, const uint32_t* __restrict__ ccl,
                          const uint32_t* __restrict__ ccv, const float* __restrict__ ccb,
                          float* __restrict__ ss, uint32_t* __restrict__ sl,
                          uint32_t* __restrict__ sv, float* __restrict__ sb,
                          uint32_t* __restrict__ maxcb) {
  int b = blockIdx.y;
  __shared__ uint32_t key[KTOT];   // 18.9 KB
  int tid = threadIdx.x;
  for (int e = tid; e < KTOT; e += 256) key[e] = f2s(ccs[(size_t)b * KTOT + e]);
  __syncthreads();
  int e = blockIdx.x * 256 + tid;
  if (e >= KTOT) return;
  uint32_t ke = key[e];
  int rank = 0;
  const uint4* k4 = (const uint4*)key;
  for (int j4 = 0; j4 < KTOT / 4; j4++) {
    uint4 kk = k4[j4];
    int j = j4 * 4;
    rank += ((kk.x > ke) || (kk.x == ke && (j + 0) < e)) ? 1 : 0;
    rank += ((kk.y > ke) || (kk.y == ke && (j + 1) < e)) ? 1 : 0;
    rank += ((kk.z > ke) || (kk.z == ke && (j + 2) < e)) ? 1 : 0;
    rank += ((kk.w > ke) || (kk.w == ke && (j + 3) < e)) ? 1 : 0;
  }
  int sidx = b * KTOT + e;
  int d = b * KTOT + rank;
  ss[d] = ccs[sidx];
  sl[d] = ccl[sidx];
  sv[d] = ccv[sidx];
  float b0 = ccb[(size_t)sidx * 4 + 0], b1 = ccb[(size_t)sidx * 4 + 1];
  float b2 = ccb[(size_t)sidx * 4 + 2], b3 = ccb[(size_t)sidx * 4 + 3];
  sb[(size_t)d * 4 + 0] = b0; sb[(size_t)d * 4 + 1] = b1;
  sb[(size_t)d * 4 + 2] = b2; sb[(size_t)d * 4 + 3] = b3;
  float mx = fmaxf(fmaxf(b0, b1), fmaxf(b2, b3));
  atomicMax(&maxcb[b], __float_as_uint(mx));
}

// ---------------- valid bits -> bitmask words ----------------
__global__ void k_bits(const uint32_t* __restrict__ sv, unsigned long long* __restrict__ vbits) {
  int w = blockIdx.x, b = blockIdx.y, lane = threadIdx.x;
  int e = w * 64 + lane;
  int pred = (e < KTOT) ? (sv[(size_t)b * KTOT + e] != 0u) : 0;
  unsigned long long m = __ballot(pred);
  if (lane == 0) vbits[b * NWIN + w] = m;
}

// ---------------- per-class offset boxes (f32); also zeroes paircnt -------------
__global__ void k_offset(const float* __restrict__ sb, const uint32_t* __restrict__ sl,
                         const uint32_t* __restrict__ maxcb, float* __restrict__ ob,
                         uint32_t* __restrict__ paircnt) {
  if (blockIdx.x == 0 && threadIdx.x < BN) paircnt[threadIdx.x] = 0u;
  int r = blockIdx.x * blockDim.x + threadIdx.x;
  if (r >= BN * KTOT) return;
  int b = r / KTOT;
  float scale = __fadd_rn(__uint_as_float(maxcb[b]), 1.0f);
  float offv = __fmul_rn((float)sl[r], scale);
  float x1 = __fadd_rn(sb[(size_t)r * 4 + 0], offv);
  float y1 = __fadd_rn(sb[(size_t)r * 4 + 1], offv);
  float x2 = __fadd_rn(sb[(size_t)r * 4 + 2], offv);
  float y2 = __fadd_rn(sb[(size_t)r * 4 + 3], offv);
  ob[(size_t)r * 4 + 0] = x1; ob[(size_t)r * 4 + 1] = y1;
  ob[(size_t)r * 4 + 2] = x2; ob[(size_t)r * 4 + 3] = y2;
}

// ---------------- IoU bitmask, 2D-tiled + pair emission ----------------
__global__ void k_mask(const float* __restrict__ ob, unsigned long long* __restrict__ mask,
                       unsigned long long* __restrict__ tdiag,
                       uint32_t* __restrict__ pairs, uint32_t* __restrict__ paircnt) {
  int b = blockIdx.z;
  int jt = blockIdx.y;
  int ib = blockIdx.x;
  int jbase = jt * 1024;
  int cnt = min(1024, KTOT - jbase);
  bool diagBlock = (jt == (ib >> 2));
  if (!diagBlock && (jbase + cnt - 1 <= ib * 256)) return;
  __shared__ float4 tb[1024];   // 16 KB
  int tid = threadIdx.x;
  for (int j = tid; j < cnt; j += 256)
    tb[j] = ((const float4*)ob)[(size_t)b * KTOT + jbase + j];
  __syncthreads();
  int i = ib * 256 + tid;
  bool act = (i < KTOT);
  float bx1 = 0, by1 = 0, bx2 = 0, by2 = 0, bai = 0;
  if (act) {
    float4 v = ((const float4*)ob)[(size_t)b * KTOT + i];
    bx1 = v.x; by1 = v.y; bx2 = v.z; by2 = v.w;
    bai = __fmul_rn(__fsub_rn(bx2, bx1), __fsub_rn(by2, by1));
  }
  int myw = i >> 6;
  unsigned long long dw = 0ull;
  if (act) {
    unsigned long long* mrow = mask + ((size_t)b * (KTOT + 64) + i) * NWORDS;
    int nw = (cnt + 63) >> 6;
    for (int w = 0; w < nw; w++) {
      int gw = jt * 16 + w;
      if (gw < myw) continue;
      unsigned long long bits = 0ull;
      int j0 = w * 64;
      int jn = min(64, cnt - j0);
      if (gw == myw) {
        for (int jj = 0; jj < jn; jj++) {
          if (jbase + j0 + jj > i)
            bits |= ((unsigned long long)iou_gt(bx1, by1, bx2, by2, bai, tb[j0 + jj])) << jj;
        }
        dw = bits;
      } else {
        for (int jj = 0; jj < jn; jj++)
          bits |= ((unsigned long long)iou_gt(bx1, by1, bx2, by2, bai, tb[j0 + jj])) << jj;
        mrow[gw] = bits;
        if (bits) {   // emit sparse pairs (i<<13)|j; jword>iword by construction
          uint32_t pos = atomicAdd(&paircnt[b], (uint32_t)__popcll(bits));
          unsigned long long t = bits;
          while (t) {
            int jj = __ffsll((long long)t) - 1; t &= t - 1;
            if (pos < PAIR_CAP)
              pairs[(size_t)b * PAIR_CAP + pos] = ((uint32_t)i << 13) | (uint32_t)(jbase + j0 + jj);
            pos++;
          }
        }
      }
    }
  }
  if (diagBlock) {
    int lane = tid & 63;
    unsigned long long col = 0ull;
#pragma unroll
    for (int j = 0; j < 64; j++) {
      unsigned long long bal = __ballot((int)((dw >> j) & 1ull));
      if (lane == j) col = bal;
    }
    if (myw < NWIN) tdiag[((size_t)b * NWIN + (size_t)myw) * 64 + lane] = col;
  }
}

// ---------------- sparse-pair blocked greedy NMS, 256 thr/image -----------------
__global__ void k_nms(const unsigned long long* __restrict__ mask,
                      const unsigned long long* __restrict__ tdiag,
                      const unsigned long long* __restrict__ vbits,
                      unsigned long long* __restrict__ keepw,
                      const uint32_t* __restrict__ pairs,
                      const uint32_t* __restrict__ paircnt) {
  int b = blockIdx.x;
  int tid = threadIdx.x;
  int lane = tid & 63;
  int wv = tid >> 6;
  const unsigned long long* mb = mask + (size_t)b * (KTOT + 64) * NWORDS;
  __shared__ unsigned long long tdl[NWIN * 64];   // 37888 B
  __shared__ unsigned long long svl[NWIN];
  __shared__ unsigned long long sup[NWIN];
  __shared__ unsigned long long kwsh;
  __shared__ uint32_t plp[LDSP];                  // 49152 B
  {
    const uint4* src = (const uint4*)(tdiag + (size_t)b * NWIN * 64);
    uint4* dst = (uint4*)tdl;
#pragma unroll
    for (int s = 0; s < 10; s++) {
      int c = tid + 256 * s;
      if (c < WCH) dst[c] = src[c];
    }
  }
  if (tid < NWIN) { svl[tid] = vbits[b * NWIN + tid]; sup[tid] = 0ull; }
  uint32_t npairs = paircnt[b];
  bool useP = (npairs <= (uint32_t)PAIR_CAP);
  bool useL = (npairs <= (uint32_t)LDSP);
  const uint32_t* gpl = pairs + (size_t)b * PAIR_CAP;
  if (useL) for (uint32_t t = tid; t < npairs; t += 256) plp[t] = gpl[t];
  __syncthreads();
  unsigned int* sup32 = (unsigned int*)sup;
  if (useP) {
    // -------- sparse path: no global loads in the loop --------
    for (int w = 0; w < NWIN; w++) {
      if (wv == 0) {
        unsigned long long T = tdl[w * 64 + lane];
        unsigned long long sval = svl[w];
        unsigned long long s_in = sup[w];
        unsigned int supb = (unsigned int)((s_in >> lane) & 1ull);
        unsigned int Tlo = (unsigned int)T, Thi = (unsigned int)(T >> 32);
        unsigned int svlo = (unsigned int)sval, svhi = (unsigned int)(sval >> 32);
        unsigned long long kw = 0ull;
#pragma unroll
        for (int i = 0; i < 64; i++) {
          unsigned int si = (unsigned int)__builtin_amdgcn_readlane((int)supb, i);
          unsigned int vi = ((i < 32 ? svlo : svhi) >> (i & 31)) & 1u;
          unsigned int kp = vi & (si ^ 1u) & 1u;
          kw |= ((unsigned long long)kp) << i;
          unsigned int tbv = ((i < 32 ? Tlo : Thi) >> (i & 31)) & 1u;
          supb |= tbv & kp;
        }
        if (lane == 0) { keepw[b * NWIN + w] = kw; kwsh = kw; }
      }
      __syncthreads();
      unsigned long long kw = kwsh;
      for (uint32_t t = tid; t < npairs; t += 256) {
        uint32_t p = useL ? plp[t] : gpl[t];
        int i = (int)(p >> 13);
        if ((i >> 6) != w) continue;
        if (!((kw >> (i & 63)) & 1ull)) continue;
        int j = (int)(p & 8191u);
        atomicOr(&sup32[j >> 5], 1u << (j & 31));
      }
      __syncthreads();
    }
  } else {
    // -------- dense fallback (R11) --------
    for (int w = 0; w < NWIN; w++) {
      uint4 q[10];
      const uint4* src4 = (const uint4*)(mb + (size_t)w * 64 * NWORDS);
#pragma unroll
      for (int s = 0; s < 10; s++) {
        int c = tid + 256 * s;
        if (c < WCH && (2 * (c % 37) + 1 > w)) q[s] = src4[c];
      }
      if (wv == 0) {
        unsigned long long T = tdl[w * 64 + lane];
        unsigned long long sval = svl[w];
        unsigned long long s_in = sup[w];
        unsigned int supb = (unsigned int)((s_in >> lane) & 1ull);
        unsigned int Tlo = (unsigned int)T, Thi = (unsigned int)(T >> 32);
        unsigned int svlo = (unsigned int)sval, svhi = (unsigned int)(sval >> 32);
        unsigned long long kw = 0ull;
#pragma unroll
        for (int i = 0; i < 64; i++) {
          unsigned int si = (unsigned int)__builtin_amdgcn_readlane((int)supb, i);
          unsigned int vi = ((i < 32 ? svlo : svhi) >> (i & 31)) & 1u;
          unsigned int kp = vi & (si ^ 1u) & 1u;
          kw |= ((unsigned long long)kp) << i;
          unsigned int tbv = ((i < 32 ? Tlo : Thi) >> (i & 31)) & 1u;
          supb |= tbv & kp;
        }
        if (lane == 0) { keepw[b * NWIN + w] = kw; kwsh = kw; }
      }
      __syncthreads();
      unsigned long long kw = kwsh;
#pragma unroll
      for (int s = 0; s < 10; s++) {
        int c = tid + 256 * s;
        if (c >= WCH) continue;
        int wp = c % 37;
        if (2 * wp + 1 <= w) continue;
        int r = c / 37;
        if (!((kw >> r) & 1ull)) continue;
        int wlo = 2 * wp, whi = 2 * wp + 1;
        if (wlo > w) {
          if (q[s].x) atomicOr(&sup32[2 * wlo + 0], q[s].x);
          if (q[s].y) atomicOr(&sup32[2 * wlo + 1], q[s].y);
        }
        if (whi > w) {
          if (q[s].z) atomicOr(&sup32[2 * whi + 0], q[s].z);
          if (q[s].w) atomicOr(&sup32[2 * whi + 1], q[s].w);
        }
      }
      __syncthreads();
    }
  }
}

// ---------------- final outputs ----------------
__global__ void k_out(const float* __restrict__ ss, const uint32_t* __restrict__ sl,
                      const float* __restrict__ sb, const unsigned long long* __restrict__ keepw,
                      float* __restrict__ out) {
  int r = blockIdx.x * blockDim.x + threadIdx.x;
  if (r >= BN * KTOT) return;
  int b = r / KTOT;
  int e = r - b * KTOT;
  unsigned int kp = (unsigned int)((keepw[b * NWIN + (e >> 6)] >> (e & 63)) & 1ull);
  out[(size_t)r * 5 + 0] = sb[(size_t)r * 4 + 0];
  out[(size_t)r * 5 + 1] = sb[(size_t)r * 4 + 1];
  out[(size_t)r * 5 + 2] = sb[(size_t)r * 4 + 2];
  out[(size_t)r * 5 + 3] = sb[(size_t)r * 4 + 3];
  out[(size_t)r * 5 + 4] = ss[r];
  out[(size_t)BN * KTOT * 5 + r] = (float)sl[r];
  out[(size_t)BN * KTOT * 6 + r] = kp ? 1.0f : 0.0f;
}

extern "C" void kernel_launch(void* const* d_in, const int* in_sizes, int n_in,
                              void* d_out, int out_size, void* d_ws, size_t ws_size,
                              hipStream_t stream) {
  InPtrs ip;
  for (int l = 0; l < 5; l++) {
    ip.cls[l]  = (const float*)d_in[3 * l + 0];
    ip.bbox[l] = (const float*)d_in[3 * l + 1];
    ip.ctr[l]  = (const float*)d_in[3 * l + 2];
  }

  size_t off = 0;
  auto alloc = [&](size_t n) {
    char* p = (char*)d_ws + off;
    off = (off + n + 255) & ~(size_t)255;
    return p;
  };
  // region0: su + hist + small counters (phase A) overlaid with padded mask
  // (phase B). Small counters (selcnt/tiecnt/maxcb) are consumed before
  // k_mask writes the mask over them.
  const size_t SU_BYTES   = (size_t)BN * TOT * 4;                  // 2.73 MB
  const size_t HIST_BYTES = 20ull * 65536 * 4;                     // 5.24 MB
  const size_t EXTRA      = 256;                                   // selcnt/tiecnt/maxcb
  const size_t MASK_BYTES = (size_t)BN * (KTOT + 64) * NWORDS * 8; // 11.3 MB
  size_t region0 = ((SU_BYTES + 255) & ~(size_t)255) + HIST_BYTES + EXTRA;
  if (MASK_BYTES > region0) region0 = MASK_BYTES;
  char* r0p = (char*)alloc(region0);
  uint32_t* su   = (uint32_t*)r0p;
  uint32_t* hist = (uint32_t*)(r0p + ((SU_BYTES + 255) & ~(size_t)255));
  uint32_t* selcnt = hist + 20ull * 65536;
  uint32_t* tiecnt = selcnt + 20;
  uint32_t* maxcb  = tiecnt + 20;
  unsigned long long* mask = (unsigned long long*)r0p;

  uint32_t* mpfx   = (uint32_t*)alloc(20 * 4);
  uint32_t* mk     = (uint32_t*)alloc(20 * 4);
  uint32_t* selu   = (uint32_t*)alloc(20ull * 1024 * 4);
  uint32_t* seli   = (uint32_t*)alloc(20ull * 1024 * 4);
  uint32_t* tiei   = (uint32_t*)alloc(20ull * TIE_CAP * 4);
  float*    ccs    = (float*)   alloc((size_t)BN * KTOT * 4);
  uint32_t* ccl    = (uint32_t*)alloc((size_t)BN * KTOT * 4);
  uint32_t* ccv    = (uint32_t*)alloc((size_t)BN * KTOT * 4);
  float*    ccb    = (float*)   alloc((size_t)BN * KTOT * 16);
  float*    ss     = (float*)   alloc((size_t)BN * KTOT * 4);
  uint32_t* sl     = (uint32_t*)alloc((size_t)BN * KTOT * 4);
  uint32_t* sv     = (uint32_t*)alloc((size_t)BN * KTOT * 4);
  float*    sb     = (float*)   alloc((size_t)BN * KTOT * 16);
  float*    ob     = (float*)   alloc((size_t)BN * KTOT * 16);
  unsigned long long* tdiag = (unsigned long long*)alloc((size_t)BN * NWIN * 64 * 8); // 148 KB
  unsigned long long* vbits = (unsigned long long*)alloc((size_t)BN * NWIN * 8);
  unsigned long long* keepw = (unsigned long long*)alloc((size_t)BN * NWIN * 8);
  uint32_t* pairs   = (uint32_t*)alloc((size_t)BN * PAIR_CAP * 4);  // 2 MB
  uint32_t* paircnt = (uint32_t*)alloc(BN * 4);
  (void)ws_size; (void)in_sizes; (void)n_in; (void)out_size;

  dim3 gscan((TOT + 255) / 256, BN);
  hipMemsetAsync(hist, 0, HIST_BYTES + EXTRA, stream);   // hist + counters
  k_score<<<gscan, 256, 0, stream>>>(ip, su, hist);
  k_findp<<<20, 1024, 0, stream>>>(hist, mpfx, mk, 0);
  hipMemsetAsync(hist, 0, HIST_BYTES, stream);
  k_hist1<<<gscan, 256, 0, stream>>>(su, mpfx, hist);
  k_findp<<<20, 1024, 0, stream>>>(hist, mpfx, mk, 1);
  k_compact<<<gscan, 256, 0, stream>>>(su, mpfx, selcnt, tiecnt, selu, seli, tiei);
  k_ties<<<20, 256, 0, stream>>>(mpfx, mk, tiecnt, tiei, selu, seli);
  k_emit<<<dim3(20, 4), 256, 0, stream>>>(ip, selu, seli, ccs, ccl, ccv, ccb);
  k_sortimg<<<dim3(19, BN), 256, 0, stream>>>(ccs, ccl, ccv, ccb, ss, sl, sv, sb, maxcb);
  k_bits<<<dim3(NWIN, BN), 64, 0, stream>>>(sv, vbits);
  k_offset<<<(BN * KTOT + 255) / 256, 256, 0, stream>>>(sb, sl, maxcb, ob, paircnt);
  k_mask<<<dim3(19, 5, BN), 256, 0, stream>>>(ob, mask, tdiag, pairs, paircnt);
  k_nms<<<BN, 256, 0, stream>>>(mask, tdiag, vbits, keepw, pairs, paircnt);
  k_out<<<(BN * KTOT + 255) / 256, 256, 0, stream>>>(ss, sl, sb, keepw, (float*)d_out);
}